// Round 1
// baseline (5850.768 us; speedup 1.0000x reference)
//
#include <hip/hip_runtime.h>
#include <hip/hip_bf16.h>

#define D 128
#define EPSV 1e-5f

typedef __attribute__((ext_vector_type(8))) short bf16x8;
typedef __attribute__((ext_vector_type(4))) float f32x4;

__device__ inline unsigned short f2bf(float f) {
    unsigned int u = __builtin_bit_cast(unsigned int, f);
    return (unsigned short)((u + 0x7fffu + ((u >> 16) & 1u)) >> 16);
}

__device__ inline bf16x8 cvt8(float4 a, float4 b) {
    bf16x8 f;
    f[0] = (short)f2bf(a.x); f[1] = (short)f2bf(a.y);
    f[2] = (short)f2bf(a.z); f[3] = (short)f2bf(a.w);
    f[4] = (short)f2bf(b.x); f[5] = (short)f2bf(b.y);
    f[6] = (short)f2bf(b.z); f[7] = (short)f2bf(b.w);
    return f;
}

__device__ inline float4 scal4(float4 a, float s) {
    return make_float4(a.x * s, a.y * s, a.z * s, a.w * s);
}
__device__ inline float4 fma4(float4 a, float4 s, float4 t) {
    return make_float4(a.x * s.x + t.x, a.y * s.y + t.y, a.z * s.z + t.z, a.w * s.w + t.w);
}

// ---- degree: one float atomic per edge ----
__global__ void k_deg(const int* __restrict__ dst, int E, float* __restrict__ deg) {
    int i = blockIdx.x * blockDim.x + threadIdx.x;
    int stride = gridDim.x * blockDim.x;
    for (; i < E; i += stride) unsafeAtomicAdd(&deg[dst[i]], 1.0f);
}

// ---- scatter-add: 32 lanes per edge, float4 per lane ----
__global__ void k_scatter(const float* __restrict__ feat, const int* __restrict__ srcI,
                          const int* __restrict__ dstI, int E, float* __restrict__ msg) {
    long long gid = (long long)blockIdx.x * blockDim.x + threadIdx.x;
    int sub = (int)(gid & 31);
    long long e = gid >> 5;
    long long estride = ((long long)gridDim.x * blockDim.x) >> 5;
    for (; e < E; e += estride) {
        int s = srcI[e], d = dstI[e];
        float4 v = *(const float4*)(feat + (size_t)s * D + sub * 4);
        float* p = msg + (size_t)d * D + sub * 4;
        unsafeAtomicAdd(p + 0, v.x);
        unsafeAtomicAdd(p + 1, v.y);
        unsafeAtomicAdd(p + 2, v.z);
        unsafeAtomicAdd(p + 3, v.w);
    }
}

// ---- fused GEMM: C = act( rowscale(A1) @ W1^T [+ A2 @ W2^T] + bias ), all [M,128]x[128,128]
// TWO: add A2@W2^T;  RELU: relu output;  RS: A1 row-scaled by 1/max(deg,1);  KA: per-K affine on A1
template <int TWO, int RELU, int RS, int KA>
__global__ __launch_bounds__(256) void k_gemm(
    const float* __restrict__ A1, const float* __restrict__ A2,
    const float* __restrict__ W1, const float* __restrict__ W2,
    const float* __restrict__ bias, const float* __restrict__ deg,
    const float* __restrict__ ka, float* __restrict__ C, int M) {
    int lane = threadIdx.x & 63;
    int wave = threadIdx.x >> 6;
    int m0 = blockIdx.x * 64 + wave * 16;
    int rlo = lane & 15;
    int k0 = (lane >> 4) * 8;
    int ra = m0 + rlo;
    if (ra > M - 1) ra = M - 1;
    float rs = 1.0f;
    if (RS) { float dg = deg[ra]; rs = 1.0f / fmaxf(dg, 1.0f); }

    // A1 fragments: lane holds row (l&15), k = kk*32 + (l>>4)*8 + j
    bf16x8 afrag[4];
    {
        const float* arow = A1 + (size_t)ra * D;
        #pragma unroll
        for (int kk = 0; kk < 4; kk++) {
            int kb = kk * 32 + k0;
            float4 v0 = *(const float4*)(arow + kb);
            float4 v1 = *(const float4*)(arow + kb + 4);
            if (RS) { v0 = scal4(v0, rs); v1 = scal4(v1, rs); }
            if (KA) {
                float4 s0 = *(const float4*)(ka + kb);
                float4 s1 = *(const float4*)(ka + kb + 4);
                float4 t0 = *(const float4*)(ka + 128 + kb);
                float4 t1 = *(const float4*)(ka + 128 + kb + 4);
                v0 = fma4(v0, s0, t0);
                v1 = fma4(v1, s1, t1);
            }
            afrag[kk] = cvt8(v0, v1);
        }
    }

    f32x4 acc[8];
    #pragma unroll
    for (int nt = 0; nt < 8; nt++) acc[nt] = (f32x4){0.f, 0.f, 0.f, 0.f};

    // B fragment for C = A @ W^T: B[k][n] = W[n][k] -> lane reads W row (nt*16 + l&15), cols kb..kb+7
    #pragma unroll
    for (int nt = 0; nt < 8; nt++) {
        const float* wrow = W1 + (size_t)(nt * 16 + rlo) * D;
        #pragma unroll
        for (int kk = 0; kk < 4; kk++) {
            int kb = kk * 32 + k0;
            float4 v0 = *(const float4*)(wrow + kb);
            float4 v1 = *(const float4*)(wrow + kb + 4);
            bf16x8 bfrag = cvt8(v0, v1);
            acc[nt] = __builtin_amdgcn_mfma_f32_16x16x32_bf16(afrag[kk], bfrag, acc[nt], 0, 0, 0);
        }
    }

    if (TWO) {
        bf16x8 afrag2[4];
        const float* arow2 = A2 + (size_t)ra * D;
        #pragma unroll
        for (int kk = 0; kk < 4; kk++) {
            int kb = kk * 32 + k0;
            float4 v0 = *(const float4*)(arow2 + kb);
            float4 v1 = *(const float4*)(arow2 + kb + 4);
            afrag2[kk] = cvt8(v0, v1);
        }
        #pragma unroll
        for (int nt = 0; nt < 8; nt++) {
            const float* wrow = W2 + (size_t)(nt * 16 + rlo) * D;
            #pragma unroll
            for (int kk = 0; kk < 4; kk++) {
                int kb = kk * 32 + k0;
                float4 v0 = *(const float4*)(wrow + kb);
                float4 v1 = *(const float4*)(wrow + kb + 4);
                bf16x8 bfrag = cvt8(v0, v1);
                acc[nt] = __builtin_amdgcn_mfma_f32_16x16x32_bf16(afrag2[kk], bfrag, acc[nt], 0, 0, 0);
            }
        }
    }

    // C/D layout: col = lane&15, row = (lane>>4)*4 + r
    #pragma unroll
    for (int nt = 0; nt < 8; nt++) {
        int col = nt * 16 + rlo;
        float bn = bias[col];
        #pragma unroll
        for (int r = 0; r < 4; r++) {
            int row = m0 + (lane >> 4) * 4 + r;
            if (row < M) {
                float v = acc[nt][r] + bn;
                if (RELU) v = fmaxf(v, 0.0f);
                C[(size_t)row * D + col] = v;
            }
        }
    }
}

// ---- batchnorm stats: per-column sum & sumsq via per-thread partials + atomics ----
__global__ void k_bnstats(const float* __restrict__ h, int M, float* __restrict__ stats) {
    int col = threadIdx.x & 127;
    int rpb = blockDim.x >> 7;
    int r = blockIdx.x * rpb + (threadIdx.x >> 7);
    int stride = gridDim.x * rpb;
    float s = 0.f, s2 = 0.f;
    for (; r < M; r += stride) {
        float v = h[(size_t)r * D + col];
        s += v;
        s2 += v * v;
    }
    unsafeAtomicAdd(&stats[col], s);
    unsafeAtomicAdd(&stats[128 + col], s2);
}

__global__ void k_bnfinal(const float* __restrict__ stats, const float* __restrict__ gamma,
                          const float* __restrict__ beta, int M, float* __restrict__ ss) {
    int k = threadIdx.x;
    if (k < 128) {
        float mu = stats[k] / (float)M;
        float var = stats[128 + k] / (float)M - mu * mu;
        float sc = gamma[k] * rsqrtf(var + EPSV);
        ss[k] = sc;
        ss[128 + k] = beta[k] - mu * sc;
    }
}

extern "C" void kernel_launch(void* const* d_in, const int* in_sizes, int n_in,
                              void* d_out, int out_size, void* d_ws, size_t ws_size,
                              hipStream_t stream) {
    const float* x   = (const float*)d_in[0];
    const int*   ei  = (const int*)d_in[1];
    const float* Wl1 = (const float*)d_in[2];
    const float* bl1 = (const float*)d_in[3];
    const float* Wr1 = (const float*)d_in[4];
    const float* Wl2 = (const float*)d_in[5];
    const float* bl2 = (const float*)d_in[6];
    const float* Wr2 = (const float*)d_in[7];
    const float* gamma = (const float*)d_in[8];
    const float* beta  = (const float*)d_in[9];
    const float* fcW = (const float*)d_in[10];
    const float* fcb = (const float*)d_in[11];
    float* out = (float*)d_out;

    const int M = in_sizes[0] / D;
    const int E = in_sizes[1] / 2;
    const int* srcI = ei;
    const int* dstI = ei + E;

    float* ws = (float*)d_ws;
    float* deg = ws;                         // M
    float* msg = ws + M;                     // M*D
    float* h1  = msg + (size_t)M * D;        // M*D
    float* h2  = h1 + (size_t)M * D;         // M*D
    float* stats = h2 + (size_t)M * D;       // 256
    float* ss    = stats + 256;              // 256

    const int gemm_grid = (M + 63) / 64;

    // layer 1
    hipMemsetAsync(deg, 0, (size_t)M * sizeof(float), stream);
    hipMemsetAsync(msg, 0, (size_t)M * D * sizeof(float), stream);
    hipMemsetAsync(stats, 0, 256 * sizeof(float), stream);
    k_deg<<<1024, 256, 0, stream>>>(dstI, E, deg);
    k_scatter<<<4096, 256, 0, stream>>>(x, srcI, dstI, E, msg);
    k_gemm<1, 1, 1, 0><<<gemm_grid, 256, 0, stream>>>(msg, x, Wl1, Wr1, bl1, deg, nullptr, h1, M);

    // layer 2
    hipMemsetAsync(msg, 0, (size_t)M * D * sizeof(float), stream);
    k_scatter<<<4096, 256, 0, stream>>>(h1, srcI, dstI, E, msg);
    k_gemm<1, 1, 1, 0><<<gemm_grid, 256, 0, stream>>>(msg, h1, Wl2, Wr2, bl2, deg, nullptr, h2, M);

    // batchnorm
    k_bnstats<<<1024, 256, 0, stream>>>(h2, M, stats);
    k_bnfinal<<<1, 128, 0, stream>>>(stats, gamma, beta, M, ss);

    // final fc with folded BN affine
    k_gemm<0, 0, 0, 1><<<gemm_grid, 256, 0, stream>>>(h2, nullptr, fcW, nullptr, fcb, nullptr, ss, out, M);
}

// Round 3
// 919.694 us; speedup vs baseline: 6.3616x; 6.3616x over previous
//
#include <hip/hip_runtime.h>
#include <hip/hip_bf16.h>

#define D 128
#define EPSV 1e-5f
#define CHUNK 4096

typedef __attribute__((ext_vector_type(8))) short bf16x8;
typedef __attribute__((ext_vector_type(4))) float f32x4;

__device__ inline unsigned short f2bf(float f) {
    unsigned int u = __builtin_bit_cast(unsigned int, f);
    return (unsigned short)((u + 0x7fffu + ((u >> 16) & 1u)) >> 16);
}

__device__ inline bf16x8 cvt8(float4 a, float4 b) {
    bf16x8 f;
    f[0] = (short)f2bf(a.x); f[1] = (short)f2bf(a.y);
    f[2] = (short)f2bf(a.z); f[3] = (short)f2bf(a.w);
    f[4] = (short)f2bf(b.x); f[5] = (short)f2bf(b.y);
    f[6] = (short)f2bf(b.z); f[7] = (short)f2bf(b.w);
    return f;
}

__device__ inline float4 fma4(float4 a, float4 s, float4 t) {
    return make_float4(a.x * s.x + t.x, a.y * s.y + t.y, a.z * s.z + t.z, a.w * s.w + t.w);
}

// ---------- CSR build ----------
__global__ void k_hist(const int* __restrict__ dst, int E, int* __restrict__ counts) {
    int i = blockIdx.x * blockDim.x + threadIdx.x;
    int stride = gridDim.x * blockDim.x;
    for (; i < E; i += stride) atomicAdd(&counts[dst[i]], 1);
}

__global__ void k_scanA(const int* __restrict__ counts, int M, int* __restrict__ partials) {
    __shared__ int sm[256];
    int t = threadIdx.x;
    int base = blockIdx.x * CHUNK + t * 16;
    int s = 0;
    #pragma unroll
    for (int j = 0; j < 16; j++) { int i = base + j; if (i < M) s += counts[i]; }
    sm[t] = s; __syncthreads();
    for (int off = 128; off > 0; off >>= 1) {
        if (t < off) sm[t] += sm[t + off];
        __syncthreads();
    }
    if (t == 0) partials[blockIdx.x] = sm[0];
}

__global__ void k_scanB(int* __restrict__ partials, int nb, int* __restrict__ row_ptr, int M, int E) {
    if (threadIdx.x == 0) {
        int run = 0;
        for (int i = 0; i < nb; i++) { int v = partials[i]; partials[i] = run; run += v; }
        row_ptr[M] = E;
    }
}

// reads counts, writes row_ptr and cursor (cursor may alias counts)
__global__ void k_scanC(const int* __restrict__ counts, int M, const int* __restrict__ partials,
                        int* __restrict__ row_ptr, int* __restrict__ cursor) {
    __shared__ int sm[256];
    int t = threadIdx.x;
    int base = blockIdx.x * CHUNK + t * 16;
    int loc[16];
    int s = 0;
    #pragma unroll
    for (int j = 0; j < 16; j++) {
        int i = base + j;
        int v = (i < M) ? counts[i] : 0;
        loc[j] = s; s += v;
    }
    sm[t] = s; __syncthreads();
    int mysum = s;
    for (int off = 1; off < 256; off <<= 1) {
        int add = (t >= off) ? sm[t - off] : 0;
        __syncthreads();
        sm[t] += add;
        __syncthreads();
    }
    int thread_excl = sm[t] - mysum;
    int boff = partials[blockIdx.x];
    #pragma unroll
    for (int j = 0; j < 16; j++) {
        int i = base + j;
        if (i < M) {
            int rp = boff + thread_excl + loc[j];
            row_ptr[i] = rp;
            cursor[i] = rp;
        }
    }
}

__global__ void k_fill(const int* __restrict__ src, const int* __restrict__ dst, int E,
                       int* __restrict__ cursor, int* __restrict__ csr) {
    int i = blockIdx.x * blockDim.x + threadIdx.x;
    int stride = gridDim.x * blockDim.x;
    for (; i < E; i += stride) {
        int d = dst[i];
        int pos = atomicAdd(&cursor[d], 1);
        csr[pos] = src[i];
    }
}

// ---------- gather-aggregate: 32-lane sub-wave per node, mean over neighbors ----------
__global__ __launch_bounds__(256) void k_gather(const float* __restrict__ feat, const int* __restrict__ rp,
                                                const int* __restrict__ csr, float* __restrict__ msg, int M) {
    int sub = threadIdx.x & 31;
    int node = blockIdx.x * 8 + (threadIdx.x >> 5);
    if (node >= M) return;
    int beg = rp[node], end = rp[node + 1];
    float4 a0 = make_float4(0.f, 0.f, 0.f, 0.f);
    float4 a1 = make_float4(0.f, 0.f, 0.f, 0.f);
    int e = beg;
    for (; e + 1 < end; e += 2) {
        int s0 = csr[e], s1 = csr[e + 1];
        float4 v0 = *(const float4*)(feat + (size_t)s0 * D + sub * 4);
        float4 v1 = *(const float4*)(feat + (size_t)s1 * D + sub * 4);
        a0.x += v0.x; a0.y += v0.y; a0.z += v0.z; a0.w += v0.w;
        a1.x += v1.x; a1.y += v1.y; a1.z += v1.z; a1.w += v1.w;
    }
    if (e < end) {
        int s0 = csr[e];
        float4 v0 = *(const float4*)(feat + (size_t)s0 * D + sub * 4);
        a0.x += v0.x; a0.y += v0.y; a0.z += v0.z; a0.w += v0.w;
    }
    float inv = 1.0f / fmaxf((float)(end - beg), 1.0f);
    float4 r = make_float4((a0.x + a1.x) * inv, (a0.y + a1.y) * inv,
                           (a0.z + a1.z) * inv, (a0.w + a1.w) * inv);
    *(float4*)(msg + (size_t)node * D + sub * 4) = r;
}

// ---- fused GEMM: C = act( A1 @ W1^T [+ A2 @ W2^T] + bias ), all [M,128]x[128,128]
// TWO: add A2@W2^T;  RELU: relu output;  KA: per-K affine on A1 (folded BN)
template <int TWO, int RELU, int KA>
__global__ __launch_bounds__(256) void k_gemm(
    const float* __restrict__ A1, const float* __restrict__ A2,
    const float* __restrict__ W1, const float* __restrict__ W2,
    const float* __restrict__ bias,
    const float* __restrict__ ka, float* __restrict__ C, int M) {
    int lane = threadIdx.x & 63;
    int wave = threadIdx.x >> 6;
    int m0 = blockIdx.x * 64 + wave * 16;
    int rlo = lane & 15;
    int k0 = (lane >> 4) * 8;
    int ra = m0 + rlo;
    if (ra > M - 1) ra = M - 1;

    // A1 fragments: lane holds row (l&15), k = kk*32 + (l>>4)*8 + j
    bf16x8 afrag[4];
    {
        const float* arow = A1 + (size_t)ra * D;
        #pragma unroll
        for (int kk = 0; kk < 4; kk++) {
            int kb = kk * 32 + k0;
            float4 v0 = *(const float4*)(arow + kb);
            float4 v1 = *(const float4*)(arow + kb + 4);
            if (KA) {
                float4 s0 = *(const float4*)(ka + kb);
                float4 s1 = *(const float4*)(ka + kb + 4);
                float4 t0 = *(const float4*)(ka + 128 + kb);
                float4 t1 = *(const float4*)(ka + 128 + kb + 4);
                v0 = fma4(v0, s0, t0);
                v1 = fma4(v1, s1, t1);
            }
            afrag[kk] = cvt8(v0, v1);
        }
    }

    f32x4 acc[8];
    #pragma unroll
    for (int nt = 0; nt < 8; nt++) acc[nt] = (f32x4){0.f, 0.f, 0.f, 0.f};

    #pragma unroll
    for (int nt = 0; nt < 8; nt++) {
        const float* wrow = W1 + (size_t)(nt * 16 + rlo) * D;
        #pragma unroll
        for (int kk = 0; kk < 4; kk++) {
            int kb = kk * 32 + k0;
            float4 v0 = *(const float4*)(wrow + kb);
            float4 v1 = *(const float4*)(wrow + kb + 4);
            bf16x8 bfrag = cvt8(v0, v1);
            acc[nt] = __builtin_amdgcn_mfma_f32_16x16x32_bf16(afrag[kk], bfrag, acc[nt], 0, 0, 0);
        }
    }

    if (TWO) {
        bf16x8 afrag2[4];
        const float* arow2 = A2 + (size_t)ra * D;
        #pragma unroll
        for (int kk = 0; kk < 4; kk++) {
            int kb = kk * 32 + k0;
            float4 v0 = *(const float4*)(arow2 + kb);
            float4 v1 = *(const float4*)(arow2 + kb + 4);
            afrag2[kk] = cvt8(v0, v1);
        }
        #pragma unroll
        for (int nt = 0; nt < 8; nt++) {
            const float* wrow = W2 + (size_t)(nt * 16 + rlo) * D;
            #pragma unroll
            for (int kk = 0; kk < 4; kk++) {
                int kb = kk * 32 + k0;
                float4 v0 = *(const float4*)(wrow + kb);
                float4 v1 = *(const float4*)(wrow + kb + 4);
                bf16x8 bfrag = cvt8(v0, v1);
                acc[nt] = __builtin_amdgcn_mfma_f32_16x16x32_bf16(afrag2[kk], bfrag, acc[nt], 0, 0, 0);
            }
        }
    }

    // C/D layout: col = lane&15, row = (lane>>4)*4 + r
    #pragma unroll
    for (int nt = 0; nt < 8; nt++) {
        int col = nt * 16 + rlo;
        float bn = bias[col];
        #pragma unroll
        for (int r = 0; r < 4; r++) {
            int row = m0 + (lane >> 4) * 4 + r;
            if (row < M) {
                float v = acc[nt][r] + bn;
                if (RELU) v = fmaxf(v, 0.0f);
                C[(size_t)row * D + col] = v;
            }
        }
    }
}

// ---------- batchnorm stats ----------
__global__ void k_bnstats(const float* __restrict__ h, int M, float* __restrict__ stats) {
    int col = threadIdx.x & 127;
    int rpb = blockDim.x >> 7;
    int r = blockIdx.x * rpb + (threadIdx.x >> 7);
    int stride = gridDim.x * rpb;
    float s = 0.f, s2 = 0.f;
    for (; r < M; r += stride) {
        float v = h[(size_t)r * D + col];
        s += v;
        s2 += v * v;
    }
    unsafeAtomicAdd(&stats[col], s);
    unsafeAtomicAdd(&stats[128 + col], s2);
}

__global__ void k_bnfinal(const float* __restrict__ stats, const float* __restrict__ gamma,
                          const float* __restrict__ beta, int M, float* __restrict__ ss) {
    int k = threadIdx.x;
    if (k < 128) {
        float mu = stats[k] / (float)M;
        float var = stats[128 + k] / (float)M - mu * mu;
        float sc = gamma[k] * rsqrtf(var + EPSV);
        ss[k] = sc;
        ss[128 + k] = beta[k] - mu * sc;
    }
}

extern "C" void kernel_launch(void* const* d_in, const int* in_sizes, int n_in,
                              void* d_out, int out_size, void* d_ws, size_t ws_size,
                              hipStream_t stream) {
    const float* x   = (const float*)d_in[0];
    const int*   ei  = (const int*)d_in[1];
    const float* Wl1 = (const float*)d_in[2];
    const float* bl1 = (const float*)d_in[3];
    const float* Wr1 = (const float*)d_in[4];
    const float* Wl2 = (const float*)d_in[5];
    const float* bl2 = (const float*)d_in[6];
    const float* Wr2 = (const float*)d_in[7];
    const float* gamma = (const float*)d_in[8];
    const float* beta  = (const float*)d_in[9];
    const float* fcW = (const float*)d_in[10];
    const float* fcb = (const float*)d_in[11];
    float* out = (float*)d_out;

    const int M = in_sizes[0] / D;
    const int E = in_sizes[1] / 2;
    const int* srcI = ei;
    const int* dstI = ei + E;

    float* ws = (float*)d_ws;
    float* msg = ws;                          // M*D
    float* h1  = msg + (size_t)M * D;         // M*D
    float* h2  = h1 + (size_t)M * D;          // M*D (csr aliases this region pre-GEMM2)
    float* stats = h2 + (size_t)M * D;        // 256
    float* ss    = stats + 256;               // 256
    int* counts  = (int*)(ss + 256);          // M (reused as cursor)
    int* row_ptr = counts + M;                // M+1
    int* partials = row_ptr + M + 1;          // NB
    int* csr = (int*)h2;                      // E ints, lifetime ends before GEMM2

    const int NB = (M + CHUNK - 1) / CHUNK;
    const int gemm_grid = (M + 63) / 64;
    const int gather_grid = (M + 7) / 8;

    hipMemsetAsync(counts, 0, (size_t)M * sizeof(int), stream);
    hipMemsetAsync(stats, 0, 256 * sizeof(float), stream);

    // CSR build
    k_hist<<<1024, 256, 0, stream>>>(dstI, E, counts);
    k_scanA<<<NB, 256, 0, stream>>>(counts, M, partials);
    k_scanB<<<1, 64, 0, stream>>>(partials, NB, row_ptr, M, E);
    k_scanC<<<NB, 256, 0, stream>>>(counts, M, partials, row_ptr, counts /*cursor*/);
    k_fill<<<2048, 256, 0, stream>>>(srcI, dstI, E, counts /*cursor*/, csr);

    // layer 1
    k_gather<<<gather_grid, 256, 0, stream>>>(x, row_ptr, csr, msg, M);
    k_gemm<1, 1, 0><<<gemm_grid, 256, 0, stream>>>(msg, x, Wl1, Wr1, bl1, nullptr, h1, M);

    // layer 2
    k_gather<<<gather_grid, 256, 0, stream>>>(h1, row_ptr, csr, msg, M);
    k_gemm<1, 1, 0><<<gemm_grid, 256, 0, stream>>>(msg, h1, Wl2, Wr2, bl2, nullptr, h2, M);

    // batchnorm
    k_bnstats<<<1024, 256, 0, stream>>>(h2, M, stats);
    k_bnfinal<<<1, 128, 0, stream>>>(stats, gamma, beta, M, ss);

    // final fc with folded BN affine
    k_gemm<0, 0, 1><<<gemm_grid, 256, 0, stream>>>(h2, nullptr, fcW, nullptr, fcb, ss, out, M);
}

// Round 5
// 657.429 us; speedup vs baseline: 8.8995x; 1.3989x over previous
//
#include <hip/hip_runtime.h>
#include <hip/hip_bf16.h>

#define D 128
#define EPSV 1e-5f
#define BSH 7
#define BWIDTH 128
#define NCB 256          // chunk blocks for bucket hist/fill
#define MAXBUCK 1024

typedef __attribute__((ext_vector_type(8))) short bf16x8;
typedef __attribute__((ext_vector_type(4))) float f32x4;
typedef unsigned short u16;

__device__ inline u16 f2bf(float f) {
    unsigned int u = __builtin_bit_cast(unsigned int, f);
    return (u16)((u + 0x7fffu + ((u >> 16) & 1u)) >> 16);
}
__device__ inline float bf2f(u16 u) {
    unsigned int x = ((unsigned int)u) << 16;
    return __builtin_bit_cast(float, x);
}

// ---------- f32 -> bf16 conversion ----------
__global__ void k_cvt(const float* __restrict__ in, u16* __restrict__ out, long long n8) {
    long long i = (long long)blockIdx.x * blockDim.x + threadIdx.x;
    long long stride = (long long)gridDim.x * blockDim.x;
    for (; i < n8; i += stride) {
        const float4 v0 = *(const float4*)(in + i * 8);
        const float4 v1 = *(const float4*)(in + i * 8 + 4);
        bf16x8 o;
        o[0] = (short)f2bf(v0.x); o[1] = (short)f2bf(v0.y);
        o[2] = (short)f2bf(v0.z); o[3] = (short)f2bf(v0.w);
        o[4] = (short)f2bf(v1.x); o[5] = (short)f2bf(v1.y);
        o[6] = (short)f2bf(v1.z); o[7] = (short)f2bf(v1.w);
        *(bf16x8*)(out + i * 8) = o;
    }
}

// ---------- bucket histogram (LDS) ----------
__global__ __launch_bounds__(256) void k_bhist(const int* __restrict__ dst, int E, int chunk,
                                               int nbuck, int* __restrict__ bh) {
    __shared__ int h[MAXBUCK];
    int t = threadIdx.x;
    for (int i = t; i < nbuck; i += 256) h[i] = 0;
    __syncthreads();
    int beg = blockIdx.x * chunk, end = min(E, beg + chunk);
    for (int i = beg + t; i < end; i += 256) atomicAdd(&h[dst[i] >> BSH], 1);
    __syncthreads();
    for (int i = t; i < nbuck; i += 256) bh[(size_t)blockIdx.x * nbuck + i] = h[i];
}

// ---------- column scan: bh[b][bucket] -> exclusive prefix over b; btot[bucket]=total ----------
__global__ __launch_bounds__(NCB) void k_colscan(int* __restrict__ bh, int nbuck, int* __restrict__ btot) {
    __shared__ int sm[NCB];
    int b = blockIdx.x;
    int t = threadIdx.x;
    int v = bh[(size_t)t * nbuck + b];
    sm[t] = v;
    __syncthreads();
    for (int off = 1; off < NCB; off <<= 1) {
        int a = (t >= off) ? sm[t - off] : 0;
        __syncthreads();
        sm[t] += a;
        __syncthreads();
    }
    bh[(size_t)t * nbuck + b] = sm[t] - v;
    if (t == NCB - 1) btot[b] = sm[t];
}

// ---------- bucket-total scan -> bbase ----------
__global__ __launch_bounds__(1024) void k_btotscan(const int* __restrict__ btot, int nbuck,
                                                   int* __restrict__ bbase, int* __restrict__ row_ptr,
                                                   int M, int E) {
    __shared__ int sm[1024];
    int t = threadIdx.x;
    int v = (t < nbuck) ? btot[t] : 0;
    sm[t] = v;
    __syncthreads();
    for (int off = 1; off < 1024; off <<= 1) {
        int a = (t >= off) ? sm[t - off] : 0;
        __syncthreads();
        sm[t] += a;
        __syncthreads();
    }
    if (t < nbuck) bbase[t] = sm[t] - v;
    if (t == 0) { bbase[nbuck] = E; row_ptr[M] = E; }
}

// ---------- bucket fill: pairs[pos] = (dstlow<<24) | src ----------
__global__ __launch_bounds__(256) void k_bfill(const int* __restrict__ src, const int* __restrict__ dst,
                                               int E, int chunk, int nbuck, const int* __restrict__ bh,
                                               const int* __restrict__ bbase, unsigned int* __restrict__ pairs) {
    __shared__ int cur[MAXBUCK];
    int t = threadIdx.x;
    for (int i = t; i < nbuck; i += 256)
        cur[i] = bbase[i] + bh[(size_t)blockIdx.x * nbuck + i];
    __syncthreads();
    int beg = blockIdx.x * chunk, end = min(E, beg + chunk);
    for (int i = beg + t; i < end; i += 256) {
        int d = dst[i];
        int bk = d >> BSH;
        int pos = atomicAdd(&cur[bk], 1);
        pairs[pos] = (unsigned int)src[i] | ((unsigned int)(d & (BWIDTH - 1)) << 24);
    }
}

// ---------- per-bucket: node histogram + scan -> row_ptr, csr ----------
__global__ __launch_bounds__(256) void k_b2csr(const unsigned int* __restrict__ pairs,
                                               const int* __restrict__ bbase, int nbuck, int M,
                                               int* __restrict__ row_ptr, int* __restrict__ csr) {
    __shared__ int nh[BWIDTH];
    __shared__ int sc[BWIDTH];
    __shared__ int nc[BWIDTH];
    int b = blockIdx.x;
    int t = threadIdx.x;
    int node0 = b << BSH;
    int beg = bbase[b], end = bbase[b + 1];
    if (t < BWIDTH) nh[t] = 0;
    __syncthreads();
    for (int i = beg + t; i < end; i += 256) atomicAdd(&nh[pairs[i] >> 24], 1);
    __syncthreads();
    if (t < BWIDTH) sc[t] = nh[t];
    __syncthreads();
    for (int off = 1; off < BWIDTH; off <<= 1) {
        int a = 0;
        if (t < BWIDTH && t >= off) a = sc[t - off];
        __syncthreads();
        if (t < BWIDTH) sc[t] += a;
        __syncthreads();
    }
    if (t < BWIDTH) {
        int ex = sc[t] - nh[t];
        nc[t] = ex;
        int node = node0 + t;
        if (node < M) row_ptr[node] = beg + ex;
    }
    __syncthreads();
    for (int i = beg + t; i < end; i += 256) {
        unsigned int p = pairs[i];
        int pos = atomicAdd(&nc[p >> 24], 1);
        csr[beg + pos] = (int)(p & 0xFFFFFFu);
    }
}

// ---------- gather-aggregate (bf16 rows): 16 lanes per node ----------
__global__ __launch_bounds__(256) void k_gather(const u16* __restrict__ feat, const int* __restrict__ rp,
                                                const int* __restrict__ csr, u16* __restrict__ msg, int M) {
    int sub = threadIdx.x & 15;
    int node = blockIdx.x * 16 + (threadIdx.x >> 4);
    if (node >= M) return;
    int beg = rp[node], end = rp[node + 1];
    float a0[8], a1[8];
    #pragma unroll
    for (int j = 0; j < 8; j++) { a0[j] = 0.f; a1[j] = 0.f; }
    int e = beg;
    for (; e + 1 < end; e += 2) {
        int s0 = csr[e], s1 = csr[e + 1];
        bf16x8 v0 = *(const bf16x8*)(feat + (size_t)s0 * D + sub * 8);
        bf16x8 v1 = *(const bf16x8*)(feat + (size_t)s1 * D + sub * 8);
        #pragma unroll
        for (int j = 0; j < 8; j++) {
            a0[j] += bf2f((u16)v0[j]);
            a1[j] += bf2f((u16)v1[j]);
        }
    }
    if (e < end) {
        bf16x8 v0 = *(const bf16x8*)(feat + (size_t)csr[e] * D + sub * 8);
        #pragma unroll
        for (int j = 0; j < 8; j++) a0[j] += bf2f((u16)v0[j]);
    }
    float inv = 1.0f / fmaxf((float)(end - beg), 1.0f);
    bf16x8 o;
    #pragma unroll
    for (int j = 0; j < 8; j++) o[j] = (short)f2bf((a0[j] + a1[j]) * inv);
    *(bf16x8*)(msg + (size_t)node * D + sub * 8) = o;
}

__device__ inline bf16x8 cvt8(float4 a, float4 b) {
    bf16x8 f;
    f[0] = (short)f2bf(a.x); f[1] = (short)f2bf(a.y);
    f[2] = (short)f2bf(a.z); f[3] = (short)f2bf(a.w);
    f[4] = (short)f2bf(b.x); f[5] = (short)f2bf(b.y);
    f[6] = (short)f2bf(b.z); f[7] = (short)f2bf(b.w);
    return f;
}

// ---- fused GEMM: C = act( A1 @ W1^T [+ A2 @ W2^T] + bias ); A bf16, W f32
// TWO: add A2@W2^T; RELU; KA: per-K affine on A1 (folded BN); OUTBF: bf16 output
template <int TWO, int RELU, int KA, int OUTBF>
__global__ __launch_bounds__(256) void k_gemm(
    const u16* __restrict__ A1, const u16* __restrict__ A2,
    const float* __restrict__ W1, const float* __restrict__ W2,
    const float* __restrict__ bias, const float* __restrict__ ka,
    void* __restrict__ Cout, int M) {
    int lane = threadIdx.x & 63;
    int wave = threadIdx.x >> 6;
    int m0 = blockIdx.x * 64 + wave * 16;
    int rlo = lane & 15;
    int k0 = (lane >> 4) * 8;
    int ra = m0 + rlo;
    if (ra > M - 1) ra = M - 1;

    bf16x8 afrag[4];
    {
        const u16* arow = A1 + (size_t)ra * D;
        #pragma unroll
        for (int kk = 0; kk < 4; kk++) {
            int kb = kk * 32 + k0;
            bf16x8 raw = *(const bf16x8*)(arow + kb);
            if (KA) {
                #pragma unroll
                for (int j = 0; j < 8; j++) {
                    float f = bf2f((u16)raw[j]) * ka[kb + j] + ka[128 + kb + j];
                    raw[j] = (short)f2bf(f);
                }
            }
            afrag[kk] = raw;
        }
    }

    f32x4 acc[8];
    #pragma unroll
    for (int nt = 0; nt < 8; nt++) acc[nt] = (f32x4){0.f, 0.f, 0.f, 0.f};

    #pragma unroll
    for (int nt = 0; nt < 8; nt++) {
        const float* wrow = W1 + (size_t)(nt * 16 + rlo) * D;
        #pragma unroll
        for (int kk = 0; kk < 4; kk++) {
            int kb = kk * 32 + k0;
            float4 v0 = *(const float4*)(wrow + kb);
            float4 v1 = *(const float4*)(wrow + kb + 4);
            bf16x8 bfrag = cvt8(v0, v1);
            acc[nt] = __builtin_amdgcn_mfma_f32_16x16x32_bf16(afrag[kk], bfrag, acc[nt], 0, 0, 0);
        }
    }

    if (TWO) {
        bf16x8 afrag2[4];
        const u16* arow2 = A2 + (size_t)ra * D;
        #pragma unroll
        for (int kk = 0; kk < 4; kk++) afrag2[kk] = *(const bf16x8*)(arow2 + kk * 32 + k0);
        #pragma unroll
        for (int nt = 0; nt < 8; nt++) {
            const float* wrow = W2 + (size_t)(nt * 16 + rlo) * D;
            #pragma unroll
            for (int kk = 0; kk < 4; kk++) {
                int kb = kk * 32 + k0;
                float4 v0 = *(const float4*)(wrow + kb);
                float4 v1 = *(const float4*)(wrow + kb + 4);
                bf16x8 bfrag = cvt8(v0, v1);
                acc[nt] = __builtin_amdgcn_mfma_f32_16x16x32_bf16(afrag2[kk], bfrag, acc[nt], 0, 0, 0);
            }
        }
    }

    // C/D: col = lane&15, row = (lane>>4)*4 + r
    #pragma unroll
    for (int nt = 0; nt < 8; nt++) {
        int col = nt * 16 + rlo;
        float bn = bias[col];
        #pragma unroll
        for (int r = 0; r < 4; r++) {
            int row = m0 + (lane >> 4) * 4 + r;
            if (row < M) {
                float v = acc[nt][r] + bn;
                if (RELU) v = fmaxf(v, 0.0f);
                if (OUTBF) ((u16*)Cout)[(size_t)row * D + col] = f2bf(v);
                else       ((float*)Cout)[(size_t)row * D + col] = v;
            }
        }
    }
}

// ---------- batchnorm stats (bf16 input, LDS pre-reduce, few atomics) ----------
__global__ __launch_bounds__(256) void k_bnstats(const u16* __restrict__ h, int M, float* __restrict__ stats) {
    __shared__ float ssum[256];
    __shared__ float ssq[256];
    int col = threadIdx.x & 127;
    int half = threadIdx.x >> 7;
    float s = 0.f, s2 = 0.f;
    for (int r = blockIdx.x * 2 + half; r < M; r += 512) {
        float v = bf2f(h[(size_t)r * D + col]);
        s += v;
        s2 += v * v;
    }
    ssum[threadIdx.x] = s;
    ssq[threadIdx.x] = s2;
    __syncthreads();
    if (threadIdx.x < 128) {
        unsafeAtomicAdd(&stats[col], ssum[threadIdx.x] + ssum[threadIdx.x + 128]);
        unsafeAtomicAdd(&stats[128 + col], ssq[threadIdx.x] + ssq[threadIdx.x + 128]);
    }
}

__global__ void k_bnfinal(const float* __restrict__ stats, const float* __restrict__ gamma,
                          const float* __restrict__ beta, int M, float* __restrict__ ss) {
    int k = threadIdx.x;
    if (k < 128) {
        float mu = stats[k] / (float)M;
        float var = stats[128 + k] / (float)M - mu * mu;
        float sc = gamma[k] * rsqrtf(var + EPSV);
        ss[k] = sc;
        ss[128 + k] = beta[k] - mu * sc;
    }
}

static inline size_t alup(size_t x) { return (x + 63) & ~(size_t)63; }

extern "C" void kernel_launch(void* const* d_in, const int* in_sizes, int n_in,
                              void* d_out, int out_size, void* d_ws, size_t ws_size,
                              hipStream_t stream) {
    const float* x   = (const float*)d_in[0];
    const int*   ei  = (const int*)d_in[1];
    const float* Wl1 = (const float*)d_in[2];
    const float* bl1 = (const float*)d_in[3];
    const float* Wr1 = (const float*)d_in[4];
    const float* Wl2 = (const float*)d_in[5];
    const float* bl2 = (const float*)d_in[6];
    const float* Wr2 = (const float*)d_in[7];
    const float* gamma = (const float*)d_in[8];
    const float* beta  = (const float*)d_in[9];
    const float* fcW = (const float*)d_in[10];
    const float* fcb = (const float*)d_in[11];
    float* out = (float*)d_out;

    const int M = in_sizes[0] / D;
    const int E = in_sizes[1] / 2;
    const int* srcI = ei;
    const int* dstI = ei + E;
    const int nbuck = (M + BWIDTH - 1) >> BSH;
    const int chunk = (E + NCB - 1) / NCB;

    char* p = (char*)d_ws;
    u16* xb   = (u16*)p;            p += alup((size_t)M * D * 2);
    u16* msgb = (u16*)p;            p += alup((size_t)M * D * 2);
    u16* h1b  = (u16*)p;            p += alup((size_t)M * D * 2);
    u16* h2b  = (u16*)p;            p += alup((size_t)M * D * 2);
    unsigned int* pairs = (unsigned int*)p; p += alup((size_t)E * 4);
    int* csr  = (int*)p;            p += alup((size_t)E * 4);
    int* row_ptr = (int*)p;         p += alup((size_t)(M + 1) * 4);
    int* bh   = (int*)p;            p += alup((size_t)NCB * nbuck * 4);
    int* btot = (int*)p;            p += alup((size_t)nbuck * 4);
    int* bbase= (int*)p;            p += alup((size_t)(nbuck + 1) * 4);
    float* stats = (float*)p;       p += alup(256 * 4);
    float* ss    = (float*)p;

    const int gemm_grid = (M + 63) / 64;
    const int gather_grid = (M + 15) / 16;

    hipMemsetAsync(stats, 0, 256 * sizeof(float), stream);

    // feature conversion + CSR build
    k_cvt<<<2048, 256, 0, stream>>>(x, xb, (long long)M * D / 8);
    k_bhist<<<NCB, 256, 0, stream>>>(dstI, E, chunk, nbuck, bh);
    k_colscan<<<nbuck, NCB, 0, stream>>>(bh, nbuck, btot);
    k_btotscan<<<1, 1024, 0, stream>>>(btot, nbuck, bbase, row_ptr, M, E);
    k_bfill<<<NCB, 256, 0, stream>>>(srcI, dstI, E, chunk, nbuck, bh, bbase, pairs);
    k_b2csr<<<nbuck, 256, 0, stream>>>(pairs, bbase, nbuck, M, row_ptr, csr);

    // layer 1
    k_gather<<<gather_grid, 256, 0, stream>>>(xb, row_ptr, csr, msgb, M);
    k_gemm<1, 1, 0, 1><<<gemm_grid, 256, 0, stream>>>(msgb, xb, Wl1, Wr1, bl1, nullptr, h1b, M);

    // layer 2
    k_gather<<<gather_grid, 256, 0, stream>>>(h1b, row_ptr, csr, msgb, M);
    k_gemm<1, 1, 0, 1><<<gemm_grid, 256, 0, stream>>>(msgb, h1b, Wl2, Wr2, bl2, nullptr, h2b, M);

    // batchnorm
    k_bnstats<<<256, 256, 0, stream>>>(h2b, M, stats);
    k_bnfinal<<<1, 128, 0, stream>>>(stats, gamma, beta, M, ss);

    // final fc with folded BN affine
    k_gemm<0, 0, 1, 0><<<gemm_grid, 256, 0, stream>>>(h2b, nullptr, fcW, nullptr, fcb, ss, out, M);
}

// Round 6
// 521.182 us; speedup vs baseline: 11.2260x; 1.2614x over previous
//
#include <hip/hip_runtime.h>
#include <hip/hip_bf16.h>

#define D 128
#define EPSV 1e-5f
#define BSH 7
#define BWIDTH 128
#define NCB 256          // chunk blocks for bucket hist/fill
#define MAXBUCK 1024

typedef __attribute__((ext_vector_type(8))) short bf16x8;
typedef __attribute__((ext_vector_type(4))) float f32x4;
typedef unsigned short u16;

__device__ inline u16 f2bf(float f) {
    unsigned int u = __builtin_bit_cast(unsigned int, f);
    return (u16)((u + 0x7fffu + ((u >> 16) & 1u)) >> 16);
}
__device__ inline float bf2f(u16 u) {
    unsigned int x = ((unsigned int)u) << 16;
    return __builtin_bit_cast(float, x);
}

// ---------- f32 -> bf16 conversion ----------
__global__ void k_cvt(const float* __restrict__ in, u16* __restrict__ out, long long n8) {
    long long i = (long long)blockIdx.x * blockDim.x + threadIdx.x;
    long long stride = (long long)gridDim.x * blockDim.x;
    for (; i < n8; i += stride) {
        const float4 v0 = *(const float4*)(in + i * 8);
        const float4 v1 = *(const float4*)(in + i * 8 + 4);
        bf16x8 o;
        o[0] = (short)f2bf(v0.x); o[1] = (short)f2bf(v0.y);
        o[2] = (short)f2bf(v0.z); o[3] = (short)f2bf(v0.w);
        o[4] = (short)f2bf(v1.x); o[5] = (short)f2bf(v1.y);
        o[6] = (short)f2bf(v1.z); o[7] = (short)f2bf(v1.w);
        *(bf16x8*)(out + i * 8) = o;
    }
}

// ---------- bucket histogram (LDS) ----------
__global__ __launch_bounds__(256) void k_bhist(const int* __restrict__ dst, int E, int chunk,
                                               int nbuck, int* __restrict__ bh) {
    __shared__ int h[MAXBUCK];
    int t = threadIdx.x;
    for (int i = t; i < nbuck; i += 256) h[i] = 0;
    __syncthreads();
    int beg = blockIdx.x * chunk, end = min(E, beg + chunk);
    for (int i = beg + t; i < end; i += 256) atomicAdd(&h[dst[i] >> BSH], 1);
    __syncthreads();
    for (int i = t; i < nbuck; i += 256) bh[(size_t)blockIdx.x * nbuck + i] = h[i];
}

// ---------- column scan: bh[b][bucket] -> exclusive prefix over b; btot[bucket]=total ----------
__global__ __launch_bounds__(NCB) void k_colscan(int* __restrict__ bh, int nbuck, int* __restrict__ btot) {
    __shared__ int sm[NCB];
    int b = blockIdx.x;
    int t = threadIdx.x;
    int v = bh[(size_t)t * nbuck + b];
    sm[t] = v;
    __syncthreads();
    for (int off = 1; off < NCB; off <<= 1) {
        int a = (t >= off) ? sm[t - off] : 0;
        __syncthreads();
        sm[t] += a;
        __syncthreads();
    }
    bh[(size_t)t * nbuck + b] = sm[t] - v;
    if (t == NCB - 1) btot[b] = sm[t];
}

// ---------- bucket-total scan -> bbase ----------
__global__ __launch_bounds__(1024) void k_btotscan(const int* __restrict__ btot, int nbuck,
                                                   int* __restrict__ bbase, int* __restrict__ row_ptr,
                                                   int M, int E) {
    __shared__ int sm[1024];
    int t = threadIdx.x;
    int v = (t < nbuck) ? btot[t] : 0;
    sm[t] = v;
    __syncthreads();
    for (int off = 1; off < 1024; off <<= 1) {
        int a = (t >= off) ? sm[t - off] : 0;
        __syncthreads();
        sm[t] += a;
        __syncthreads();
    }
    if (t < nbuck) bbase[t] = sm[t] - v;
    if (t == 0) { bbase[nbuck] = E; row_ptr[M] = E; }
}

// ---------- bucket fill: pairs[pos] = (dstlow<<24) | src ----------
__global__ __launch_bounds__(256) void k_bfill(const int* __restrict__ src, const int* __restrict__ dst,
                                               int E, int chunk, int nbuck, const int* __restrict__ bh,
                                               const int* __restrict__ bbase, unsigned int* __restrict__ pairs) {
    __shared__ int cur[MAXBUCK];
    int t = threadIdx.x;
    for (int i = t; i < nbuck; i += 256)
        cur[i] = bbase[i] + bh[(size_t)blockIdx.x * nbuck + i];
    __syncthreads();
    int beg = blockIdx.x * chunk, end = min(E, beg + chunk);
    for (int i = beg + t; i < end; i += 256) {
        int d = dst[i];
        int bk = d >> BSH;
        int pos = atomicAdd(&cur[bk], 1);
        pairs[pos] = (unsigned int)src[i] | ((unsigned int)(d & (BWIDTH - 1)) << 24);
    }
}

// ---------- per-bucket: node histogram + scan -> row_ptr, csr ----------
__global__ __launch_bounds__(256) void k_b2csr(const unsigned int* __restrict__ pairs,
                                               const int* __restrict__ bbase, int nbuck, int M,
                                               int* __restrict__ row_ptr, int* __restrict__ csr) {
    __shared__ int nh[BWIDTH];
    __shared__ int sc[BWIDTH];
    __shared__ int nc[BWIDTH];
    int b = blockIdx.x;
    int t = threadIdx.x;
    int node0 = b << BSH;
    int beg = bbase[b], end = bbase[b + 1];
    if (t < BWIDTH) nh[t] = 0;
    __syncthreads();
    for (int i = beg + t; i < end; i += 256) atomicAdd(&nh[pairs[i] >> 24], 1);
    __syncthreads();
    if (t < BWIDTH) sc[t] = nh[t];
    __syncthreads();
    for (int off = 1; off < BWIDTH; off <<= 1) {
        int a = 0;
        if (t < BWIDTH && t >= off) a = sc[t - off];
        __syncthreads();
        if (t < BWIDTH) sc[t] += a;
        __syncthreads();
    }
    if (t < BWIDTH) {
        int ex = sc[t] - nh[t];
        nc[t] = ex;
        int node = node0 + t;
        if (node < M) row_ptr[node] = beg + ex;
    }
    __syncthreads();
    for (int i = beg + t; i < end; i += 256) {
        unsigned int p = pairs[i];
        int pos = atomicAdd(&nc[p >> 24], 1);
        csr[beg + pos] = (int)(p & 0xFFFFFFu);
    }
}

// ---------- gather-aggregate (bf16 rows): 16 lanes per node ----------
__global__ __launch_bounds__(256) void k_gather(const u16* __restrict__ feat, const int* __restrict__ rp,
                                                const int* __restrict__ csr, u16* __restrict__ msg, int M) {
    int sub = threadIdx.x & 15;
    int node = blockIdx.x * 16 + (threadIdx.x >> 4);
    if (node >= M) return;
    int beg = rp[node], end = rp[node + 1];
    float a0[8], a1[8];
    #pragma unroll
    for (int j = 0; j < 8; j++) { a0[j] = 0.f; a1[j] = 0.f; }
    int e = beg;
    for (; e + 1 < end; e += 2) {
        int s0 = csr[e], s1 = csr[e + 1];
        bf16x8 v0 = *(const bf16x8*)(feat + (size_t)s0 * D + sub * 8);
        bf16x8 v1 = *(const bf16x8*)(feat + (size_t)s1 * D + sub * 8);
        #pragma unroll
        for (int j = 0; j < 8; j++) {
            a0[j] += bf2f((u16)v0[j]);
            a1[j] += bf2f((u16)v1[j]);
        }
    }
    if (e < end) {
        bf16x8 v0 = *(const bf16x8*)(feat + (size_t)csr[e] * D + sub * 8);
        #pragma unroll
        for (int j = 0; j < 8; j++) a0[j] += bf2f((u16)v0[j]);
    }
    float inv = 1.0f / fmaxf((float)(end - beg), 1.0f);
    bf16x8 o;
    #pragma unroll
    for (int j = 0; j < 8; j++) o[j] = (short)f2bf((a0[j] + a1[j]) * inv);
    *(bf16x8*)(msg + (size_t)node * D + sub * 8) = o;
}

// ---- fused GEMM v2: C = act( A1 @ W1^T [+ A2 @ W2^T] + bias ); A,W bf16; MT=2 m-tiles/wave
// TWO: add A2@W2^T; RELU; OUTBF: bf16 output
template <int TWO, int RELU, int OUTBF>
__global__ __launch_bounds__(256) void k_gemm(
    const u16* __restrict__ A1, const u16* __restrict__ A2,
    const u16* __restrict__ W1b, const u16* __restrict__ W2b,
    const float* __restrict__ bias, void* __restrict__ Cout, int M) {
    int lane = threadIdx.x & 63;
    int wave = threadIdx.x >> 6;
    int rlo = lane & 15;
    int k0 = (lane >> 4) * 8;
    int m0 = blockIdx.x * 128 + wave * 32;

    f32x4 acc[2][8];
    #pragma unroll
    for (int mt = 0; mt < 2; mt++)
        #pragma unroll
        for (int nt = 0; nt < 8; nt++) acc[mt][nt] = (f32x4){0.f, 0.f, 0.f, 0.f};

    // ---- op 1: A1 @ W1^T ----
    {
        bf16x8 af[2][4];
        #pragma unroll
        for (int mt = 0; mt < 2; mt++) {
            int ra = m0 + mt * 16 + rlo;
            if (ra > M - 1) ra = M - 1;
            const u16* arow = A1 + (size_t)ra * D;
            #pragma unroll
            for (int kk = 0; kk < 4; kk++)
                af[mt][kk] = *(const bf16x8*)(arow + kk * 32 + k0);
        }
        #pragma unroll
        for (int nt = 0; nt < 8; nt++) {
            const u16* wrow = W1b + (size_t)(nt * 16 + rlo) * D;
            bf16x8 wf[4];
            #pragma unroll
            for (int kk = 0; kk < 4; kk++)
                wf[kk] = *(const bf16x8*)(wrow + kk * 32 + k0);
            #pragma unroll
            for (int mt = 0; mt < 2; mt++)
                #pragma unroll
                for (int kk = 0; kk < 4; kk++)
                    acc[mt][nt] = __builtin_amdgcn_mfma_f32_16x16x32_bf16(af[mt][kk], wf[kk], acc[mt][nt], 0, 0, 0);
        }
    }

    // ---- op 2: + A2 @ W2^T ----
    if (TWO) {
        bf16x8 af[2][4];
        #pragma unroll
        for (int mt = 0; mt < 2; mt++) {
            int ra = m0 + mt * 16 + rlo;
            if (ra > M - 1) ra = M - 1;
            const u16* arow = A2 + (size_t)ra * D;
            #pragma unroll
            for (int kk = 0; kk < 4; kk++)
                af[mt][kk] = *(const bf16x8*)(arow + kk * 32 + k0);
        }
        #pragma unroll
        for (int nt = 0; nt < 8; nt++) {
            const u16* wrow = W2b + (size_t)(nt * 16 + rlo) * D;
            bf16x8 wf[4];
            #pragma unroll
            for (int kk = 0; kk < 4; kk++)
                wf[kk] = *(const bf16x8*)(wrow + kk * 32 + k0);
            #pragma unroll
            for (int mt = 0; mt < 2; mt++)
                #pragma unroll
                for (int kk = 0; kk < 4; kk++)
                    acc[mt][nt] = __builtin_amdgcn_mfma_f32_16x16x32_bf16(af[mt][kk], wf[kk], acc[mt][nt], 0, 0, 0);
        }
    }

    // C/D: col = lane&15, row = (lane>>4)*4 + r
    #pragma unroll
    for (int mt = 0; mt < 2; mt++)
        #pragma unroll
        for (int nt = 0; nt < 8; nt++) {
            int col = nt * 16 + rlo;
            float bn = bias[col];
            #pragma unroll
            for (int r = 0; r < 4; r++) {
                int row = m0 + mt * 16 + (lane >> 4) * 4 + r;
                if (row < M) {
                    float v = acc[mt][nt][r] + bn;
                    if (RELU) v = fmaxf(v, 0.0f);
                    if (OUTBF) ((u16*)Cout)[(size_t)row * D + col] = f2bf(v);
                    else       ((float*)Cout)[(size_t)row * D + col] = v;
                }
            }
        }
}

// ---------- batchnorm stats (bf16 input, LDS pre-reduce, few atomics) ----------
__global__ __launch_bounds__(256) void k_bnstats(const u16* __restrict__ h, int M, float* __restrict__ stats) {
    __shared__ float ssum[256];
    __shared__ float ssq[256];
    int col = threadIdx.x & 127;
    int half = threadIdx.x >> 7;
    float s = 0.f, s2 = 0.f;
    for (int r = blockIdx.x * 2 + half; r < M; r += 512) {
        float v = bf2f(h[(size_t)r * D + col]);
        s += v;
        s2 += v * v;
    }
    ssum[threadIdx.x] = s;
    ssq[threadIdx.x] = s2;
    __syncthreads();
    if (threadIdx.x < 128) {
        unsafeAtomicAdd(&stats[col], ssum[threadIdx.x] + ssum[threadIdx.x + 128]);
        unsafeAtomicAdd(&stats[128 + col], ssq[threadIdx.x] + ssq[threadIdx.x + 128]);
    }
}

// ---------- BN finalize + fold affine into fcW/fcb: Wfold[n][k]=bf16(fcW[n][k]*sc[k]),
// bias2[n] = fcb[n] + sum_k sh[k]*fcW[n][k]
__global__ __launch_bounds__(128) void k_bnfold(const float* __restrict__ stats,
                                                const float* __restrict__ gamma, const float* __restrict__ beta,
                                                const float* __restrict__ fcW, const float* __restrict__ fcb,
                                                int M, u16* __restrict__ Wfold, float* __restrict__ bias2) {
    __shared__ float sc[128], sh[128];
    int t = threadIdx.x;
    float mu = stats[t] / (float)M;
    float var = stats[128 + t] / (float)M - mu * mu;
    float s = gamma[t] * rsqrtf(var + EPSV);
    sc[t] = s;
    sh[t] = beta[t] - mu * s;
    __syncthreads();
    const float* wrow = fcW + (size_t)t * 128;
    float accv = fcb[t];
    #pragma unroll 4
    for (int k = 0; k < 128; k++) {
        float w = wrow[k];
        Wfold[(size_t)t * 128 + k] = f2bf(w * sc[k]);
        accv += sh[k] * w;
    }
    bias2[t] = accv;
}

static inline size_t alup(size_t x) { return (x + 63) & ~(size_t)63; }

extern "C" void kernel_launch(void* const* d_in, const int* in_sizes, int n_in,
                              void* d_out, int out_size, void* d_ws, size_t ws_size,
                              hipStream_t stream) {
    const float* x   = (const float*)d_in[0];
    const int*   ei  = (const int*)d_in[1];
    const float* Wl1 = (const float*)d_in[2];
    const float* bl1 = (const float*)d_in[3];
    const float* Wr1 = (const float*)d_in[4];
    const float* Wl2 = (const float*)d_in[5];
    const float* bl2 = (const float*)d_in[6];
    const float* Wr2 = (const float*)d_in[7];
    const float* gamma = (const float*)d_in[8];
    const float* beta  = (const float*)d_in[9];
    const float* fcW = (const float*)d_in[10];
    const float* fcb = (const float*)d_in[11];
    float* out = (float*)d_out;

    const int M = in_sizes[0] / D;
    const int E = in_sizes[1] / 2;
    const int* srcI = ei;
    const int* dstI = ei + E;
    const int nbuck = (M + BWIDTH - 1) >> BSH;
    const int chunk = (E + NCB - 1) / NCB;

    char* p = (char*)d_ws;
    u16* xb   = (u16*)p;            p += alup((size_t)M * D * 2);
    u16* msgb = (u16*)p;            p += alup((size_t)M * D * 2);
    u16* h1b  = (u16*)p;            p += alup((size_t)M * D * 2);
    u16* h2b  = (u16*)p;            p += alup((size_t)M * D * 2);
    unsigned int* pairs = (unsigned int*)p; p += alup((size_t)E * 4);
    int* csr  = (int*)p;            p += alup((size_t)E * 4);
    int* row_ptr = (int*)p;         p += alup((size_t)(M + 1) * 4);
    int* bh   = (int*)p;            p += alup((size_t)NCB * nbuck * 4);
    int* btot = (int*)p;            p += alup((size_t)nbuck * 4);
    int* bbase= (int*)p;            p += alup((size_t)(nbuck + 1) * 4);
    float* stats = (float*)p;       p += alup(256 * 4);
    u16* Wl1b = (u16*)p;            p += alup((size_t)D * D * 2);
    u16* Wr1b = (u16*)p;            p += alup((size_t)D * D * 2);
    u16* Wl2b = (u16*)p;            p += alup((size_t)D * D * 2);
    u16* Wr2b = (u16*)p;            p += alup((size_t)D * D * 2);
    u16* Wfoldb = (u16*)p;          p += alup((size_t)D * D * 2);
    float* bias2 = (float*)p;       p += alup(128 * 4);

    const int gemm_grid = (M + 127) / 128;
    const int gather_grid = (M + 15) / 16;
    const long long wn8 = (long long)D * D / 8;

    hipMemsetAsync(stats, 0, 256 * sizeof(float), stream);

    // conversions + CSR build
    k_cvt<<<2048, 256, 0, stream>>>(x, xb, (long long)M * D / 8);
    k_cvt<<<8, 256, 0, stream>>>(Wl1, Wl1b, wn8);
    k_cvt<<<8, 256, 0, stream>>>(Wr1, Wr1b, wn8);
    k_cvt<<<8, 256, 0, stream>>>(Wl2, Wl2b, wn8);
    k_cvt<<<8, 256, 0, stream>>>(Wr2, Wr2b, wn8);
    k_bhist<<<NCB, 256, 0, stream>>>(dstI, E, chunk, nbuck, bh);
    k_colscan<<<nbuck, NCB, 0, stream>>>(bh, nbuck, btot);
    k_btotscan<<<1, 1024, 0, stream>>>(btot, nbuck, bbase, row_ptr, M, E);
    k_bfill<<<NCB, 256, 0, stream>>>(srcI, dstI, E, chunk, nbuck, bh, bbase, pairs);
    k_b2csr<<<nbuck, 256, 0, stream>>>(pairs, bbase, nbuck, M, row_ptr, csr);

    // layer 1
    k_gather<<<gather_grid, 256, 0, stream>>>(xb, row_ptr, csr, msgb, M);
    k_gemm<1, 1, 1><<<gemm_grid, 256, 0, stream>>>(msgb, xb, Wl1b, Wr1b, bl1, h1b, M);

    // layer 2
    k_gather<<<gather_grid, 256, 0, stream>>>(h1b, row_ptr, csr, msgb, M);
    k_gemm<1, 1, 1><<<gemm_grid, 256, 0, stream>>>(msgb, h1b, Wl2b, Wr2b, bl2, h2b, M);

    // batchnorm stats + fold into fc weights
    k_bnstats<<<256, 256, 0, stream>>>(h2b, M, stats);
    k_bnfold<<<1, 128, 0, stream>>>(stats, gamma, beta, fcW, fcb, M, Wfoldb, bias2);

    // final fc (BN folded into Wfold/bias2)
    k_gemm<0, 0, 0><<<gemm_grid, 256, 0, stream>>>(h2b, nullptr, Wfoldb, nullptr, bias2, out, M);
}

// Round 7
// 451.484 us; speedup vs baseline: 12.9590x; 1.1544x over previous
//
#include <hip/hip_runtime.h>
#include <hip/hip_bf16.h>

#define D 128
#define EPSV 1e-5f
#define BSH 7
#define BWIDTH 128
#define NCB 256          // chunk blocks for bucket hist/fill
#define MAXBUCK 1024

typedef __attribute__((ext_vector_type(8))) short bf16x8;
typedef __attribute__((ext_vector_type(4))) float f32x4;
typedef unsigned short u16;

__device__ inline u16 f2bf(float f) {
    unsigned int u = __builtin_bit_cast(unsigned int, f);
    return (u16)((u + 0x7fffu + ((u >> 16) & 1u)) >> 16);
}
__device__ inline float bf2f(u16 u) {
    unsigned int x = ((unsigned int)u) << 16;
    return __builtin_bit_cast(float, x);
}

// ---------- f32 -> bf16 conversion ----------
__global__ void k_cvt(const float* __restrict__ in, u16* __restrict__ out, long long n8) {
    long long i = (long long)blockIdx.x * blockDim.x + threadIdx.x;
    long long stride = (long long)gridDim.x * blockDim.x;
    for (; i < n8; i += stride) {
        const float4 v0 = *(const float4*)(in + i * 8);
        const float4 v1 = *(const float4*)(in + i * 8 + 4);
        bf16x8 o;
        o[0] = (short)f2bf(v0.x); o[1] = (short)f2bf(v0.y);
        o[2] = (short)f2bf(v0.z); o[3] = (short)f2bf(v0.w);
        o[4] = (short)f2bf(v1.x); o[5] = (short)f2bf(v1.y);
        o[6] = (short)f2bf(v1.z); o[7] = (short)f2bf(v1.w);
        *(bf16x8*)(out + i * 8) = o;
    }
}

// ---------- 4 weight matrices f32->bf16 in one launch (each 128x128) ----------
__global__ __launch_bounds__(256) void k_cvt4(const float* __restrict__ s0, const float* __restrict__ s1,
                                              const float* __restrict__ s2, const float* __restrict__ s3,
                                              u16* __restrict__ out) {
    int i = blockIdx.x * 256 + threadIdx.x;       // 8192 threads, one bf16x8 each
    int mat = i >> 11;                            // 2048 x8-chunks per matrix
    int off = (i & 2047) * 8;
    const float* src = (mat == 0) ? s0 : (mat == 1) ? s1 : (mat == 2) ? s2 : s3;
    const float4 v0 = *(const float4*)(src + off);
    const float4 v1 = *(const float4*)(src + off + 4);
    bf16x8 o;
    o[0] = (short)f2bf(v0.x); o[1] = (short)f2bf(v0.y);
    o[2] = (short)f2bf(v0.z); o[3] = (short)f2bf(v0.w);
    o[4] = (short)f2bf(v1.x); o[5] = (short)f2bf(v1.y);
    o[6] = (short)f2bf(v1.z); o[7] = (short)f2bf(v1.w);
    *(bf16x8*)(out + (size_t)i * 8) = o;
}

// ---------- bucket histogram (LDS) ----------
__global__ __launch_bounds__(256) void k_bhist(const int* __restrict__ dst, int E, int chunk,
                                               int nbuck, int* __restrict__ bh) {
    __shared__ int h[MAXBUCK];
    int t = threadIdx.x;
    for (int i = t; i < nbuck; i += 256) h[i] = 0;
    __syncthreads();
    int beg = blockIdx.x * chunk, end = min(E, beg + chunk);
    for (int i = beg + t; i < end; i += 256) atomicAdd(&h[dst[i] >> BSH], 1);
    __syncthreads();
    for (int i = t; i < nbuck; i += 256) bh[(size_t)blockIdx.x * nbuck + i] = h[i];
}

// ---------- column scan ----------
__global__ __launch_bounds__(NCB) void k_colscan(int* __restrict__ bh, int nbuck, int* __restrict__ btot) {
    __shared__ int sm[NCB];
    int b = blockIdx.x;
    int t = threadIdx.x;
    int v = bh[(size_t)t * nbuck + b];
    sm[t] = v;
    __syncthreads();
    for (int off = 1; off < NCB; off <<= 1) {
        int a = (t >= off) ? sm[t - off] : 0;
        __syncthreads();
        sm[t] += a;
        __syncthreads();
    }
    bh[(size_t)t * nbuck + b] = sm[t] - v;
    if (t == NCB - 1) btot[b] = sm[t];
}

// ---------- bucket-total scan -> bbase ----------
__global__ __launch_bounds__(1024) void k_btotscan(const int* __restrict__ btot, int nbuck,
                                                   int* __restrict__ bbase, int* __restrict__ row_ptr,
                                                   int M, int E) {
    __shared__ int sm[1024];
    int t = threadIdx.x;
    int v = (t < nbuck) ? btot[t] : 0;
    sm[t] = v;
    __syncthreads();
    for (int off = 1; off < 1024; off <<= 1) {
        int a = (t >= off) ? sm[t - off] : 0;
        __syncthreads();
        sm[t] += a;
        __syncthreads();
    }
    if (t < nbuck) bbase[t] = sm[t] - v;
    if (t == 0) { bbase[nbuck] = E; row_ptr[M] = E; }
}

// ---------- bucket fill: pairs[pos] = (dstlow<<24) | src ----------
__global__ __launch_bounds__(256) void k_bfill(const int* __restrict__ src, const int* __restrict__ dst,
                                               int E, int chunk, int nbuck, const int* __restrict__ bh,
                                               const int* __restrict__ bbase, unsigned int* __restrict__ pairs) {
    __shared__ int cur[MAXBUCK];
    int t = threadIdx.x;
    for (int i = t; i < nbuck; i += 256)
        cur[i] = bbase[i] + bh[(size_t)blockIdx.x * nbuck + i];
    __syncthreads();
    int beg = blockIdx.x * chunk, end = min(E, beg + chunk);
    for (int i = beg + t; i < end; i += 256) {
        int d = dst[i];
        int bk = d >> BSH;
        int pos = atomicAdd(&cur[bk], 1);
        pairs[pos] = (unsigned int)src[i] | ((unsigned int)(d & (BWIDTH - 1)) << 24);
    }
}

// ---------- per-bucket: node histogram + scan -> row_ptr, csr ----------
__global__ __launch_bounds__(256) void k_b2csr(const unsigned int* __restrict__ pairs,
                                               const int* __restrict__ bbase, int nbuck, int M,
                                               int* __restrict__ row_ptr, int* __restrict__ csr) {
    __shared__ int nh[BWIDTH];
    __shared__ int sc[BWIDTH];
    __shared__ int nc[BWIDTH];
    int b = blockIdx.x;
    int t = threadIdx.x;
    int node0 = b << BSH;
    int beg = bbase[b], end = bbase[b + 1];
    if (t < BWIDTH) nh[t] = 0;
    __syncthreads();
    for (int i = beg + t; i < end; i += 256) atomicAdd(&nh[pairs[i] >> 24], 1);
    __syncthreads();
    if (t < BWIDTH) sc[t] = nh[t];
    __syncthreads();
    for (int off = 1; off < BWIDTH; off <<= 1) {
        int a = 0;
        if (t < BWIDTH && t >= off) a = sc[t - off];
        __syncthreads();
        if (t < BWIDTH) sc[t] += a;
        __syncthreads();
    }
    if (t < BWIDTH) {
        int ex = sc[t] - nh[t];
        nc[t] = ex;
        int node = node0 + t;
        if (node < M) row_ptr[node] = beg + ex;
    }
    __syncthreads();
    for (int i = beg + t; i < end; i += 256) {
        unsigned int p = pairs[i];
        int pos = atomicAdd(&nc[p >> 24], 1);
        csr[beg + pos] = (int)(p & 0xFFFFFFu);
    }
}

// ---------- gather-aggregate (bf16 rows): 16 lanes per node, 4-way MLP ----------
__global__ __launch_bounds__(256) void k_gather(const u16* __restrict__ feat, const int* __restrict__ rp,
                                                const int* __restrict__ csr, u16* __restrict__ msg, int M) {
    int sub = threadIdx.x & 15;
    int node = blockIdx.x * 16 + (threadIdx.x >> 4);
    if (node >= M) return;
    int beg = rp[node], end = rp[node + 1];
    float a0[8], a1[8], a2[8], a3[8];
    #pragma unroll
    for (int j = 0; j < 8; j++) { a0[j] = 0.f; a1[j] = 0.f; a2[j] = 0.f; a3[j] = 0.f; }
    int e = beg;
    for (; e + 3 < end; e += 4) {
        int s0 = csr[e], s1 = csr[e + 1], s2 = csr[e + 2], s3 = csr[e + 3];
        bf16x8 v0 = *(const bf16x8*)(feat + (size_t)s0 * D + sub * 8);
        bf16x8 v1 = *(const bf16x8*)(feat + (size_t)s1 * D + sub * 8);
        bf16x8 v2 = *(const bf16x8*)(feat + (size_t)s2 * D + sub * 8);
        bf16x8 v3 = *(const bf16x8*)(feat + (size_t)s3 * D + sub * 8);
        #pragma unroll
        for (int j = 0; j < 8; j++) {
            a0[j] += bf2f((u16)v0[j]);
            a1[j] += bf2f((u16)v1[j]);
            a2[j] += bf2f((u16)v2[j]);
            a3[j] += bf2f((u16)v3[j]);
        }
    }
    for (; e < end; e++) {
        bf16x8 v0 = *(const bf16x8*)(feat + (size_t)csr[e] * D + sub * 8);
        #pragma unroll
        for (int j = 0; j < 8; j++) a0[j] += bf2f((u16)v0[j]);
    }
    float inv = 1.0f / fmaxf((float)(end - beg), 1.0f);
    bf16x8 o;
    #pragma unroll
    for (int j = 0; j < 8; j++) o[j] = (short)f2bf((a0[j] + a1[j] + a2[j] + a3[j]) * inv);
    *(bf16x8*)(msg + (size_t)node * D + sub * 8) = o;
}

// ---- fused GEMM v3: persistent strips, W staged in LDS (XOR-swizzled)
// C = act( A1 @ W1^T [+ A2 @ W2^T] + bias ); A,W bf16
template <int TWO, int RELU, int OUTBF>
__global__ __launch_bounds__(256) void k_gemm(
    const u16* __restrict__ A1, const u16* __restrict__ A2,
    const u16* __restrict__ W1b, const u16* __restrict__ W2b,
    const float* __restrict__ bias, void* __restrict__ Cout,
    int M, int nstrips) {
    __shared__ u16 wlds[(TWO ? 2 : 1) * 16384];
    int t = threadIdx.x;
    // stage W (row-major 128x128 bf16) with c16 ^= row&7 swizzle (16B blocks)
    {
        const int nrows = TWO ? 256 : 128;
        for (int idx = t; idx < nrows; idx += 256) {
            int mat = idx >> 7, row = idx & 127;
            const u16* g = (mat ? W2b : W1b) + (size_t)row * D;
            u16* base = wlds + mat * 16384 + row * D;
            #pragma unroll
            for (int c16 = 0; c16 < 16; c16++) {
                bf16x8 v = *(const bf16x8*)(g + c16 * 8);
                *(bf16x8*)(base + ((c16 ^ (row & 7)) * 8)) = v;
            }
        }
    }
    __syncthreads();

    int lane = t & 63, wave = t >> 6;
    int rlo = lane & 15, khi = lane >> 4;      // khi = 0..3

    for (int s = blockIdx.x; s < nstrips; s += gridDim.x) {
        int m0 = s * 128 + wave * 32;
        // A fragments: row = m0 + mt*16 + rlo, k = kk*32 + khi*8 + j
        bf16x8 a1f[2][4], a2f[2][4];
        #pragma unroll
        for (int mt = 0; mt < 2; mt++) {
            int ra = m0 + mt * 16 + rlo;
            if (ra > M - 1) ra = M - 1;
            const u16* ar = A1 + (size_t)ra * D;
            #pragma unroll
            for (int kk = 0; kk < 4; kk++)
                a1f[mt][kk] = *(const bf16x8*)(ar + kk * 32 + khi * 8);
            if (TWO) {
                const u16* ar2 = A2 + (size_t)ra * D;
                #pragma unroll
                for (int kk = 0; kk < 4; kk++)
                    a2f[mt][kk] = *(const bf16x8*)(ar2 + kk * 32 + khi * 8);
            }
        }

        f32x4 acc[2][8];
        #pragma unroll
        for (int mt = 0; mt < 2; mt++)
            #pragma unroll
            for (int nt = 0; nt < 8; nt++) acc[mt][nt] = (f32x4){0.f, 0.f, 0.f, 0.f};

        #pragma unroll
        for (int nt = 0; nt < 8; nt++) {
            int row = nt * 16 + rlo;
            const u16* wb = wlds + (size_t)row * D;
            bf16x8 wf[4];
            #pragma unroll
            for (int kk = 0; kk < 4; kk++)
                wf[kk] = *(const bf16x8*)(wb + ((kk * 4 + khi) ^ (row & 7)) * 8);
            #pragma unroll
            for (int mt = 0; mt < 2; mt++)
                #pragma unroll
                for (int kk = 0; kk < 4; kk++)
                    acc[mt][nt] = __builtin_amdgcn_mfma_f32_16x16x32_bf16(a1f[mt][kk], wf[kk], acc[mt][nt], 0, 0, 0);
            if (TWO) {
                const u16* wb2 = wlds + 16384 + (size_t)row * D;
                bf16x8 wf2[4];
                #pragma unroll
                for (int kk = 0; kk < 4; kk++)
                    wf2[kk] = *(const bf16x8*)(wb2 + ((kk * 4 + khi) ^ (row & 7)) * 8);
                #pragma unroll
                for (int mt = 0; mt < 2; mt++)
                    #pragma unroll
                    for (int kk = 0; kk < 4; kk++)
                        acc[mt][nt] = __builtin_amdgcn_mfma_f32_16x16x32_bf16(a2f[mt][kk], wf2[kk], acc[mt][nt], 0, 0, 0);
            }
        }

        // C/D: col = lane&15, row = khi*4 + r
        #pragma unroll
        for (int mt = 0; mt < 2; mt++)
            #pragma unroll
            for (int nt = 0; nt < 8; nt++) {
                int col = nt * 16 + rlo;
                float bn = bias[col];
                #pragma unroll
                for (int r = 0; r < 4; r++) {
                    int row = m0 + mt * 16 + khi * 4 + r;
                    if (row < M) {
                        float v = acc[mt][nt][r] + bn;
                        if (RELU) v = fmaxf(v, 0.0f);
                        if (OUTBF) ((u16*)Cout)[(size_t)row * D + col] = f2bf(v);
                        else       ((float*)Cout)[(size_t)row * D + col] = v;
                    }
                }
            }
    }
}

// ---------- batchnorm stats (bf16 input, LDS pre-reduce, few atomics) ----------
__global__ __launch_bounds__(256) void k_bnstats(const u16* __restrict__ h, int M, float* __restrict__ stats) {
    __shared__ float ssum[256];
    __shared__ float ssq[256];
    int col = threadIdx.x & 127;
    int half = threadIdx.x >> 7;
    float s = 0.f, s2 = 0.f;
    for (int r = blockIdx.x * 2 + half; r < M; r += 512) {
        float v = bf2f(h[(size_t)r * D + col]);
        s += v;
        s2 += v * v;
    }
    ssum[threadIdx.x] = s;
    ssq[threadIdx.x] = s2;
    __syncthreads();
    if (threadIdx.x < 128) {
        unsafeAtomicAdd(&stats[col], ssum[threadIdx.x] + ssum[threadIdx.x + 128]);
        unsafeAtomicAdd(&stats[128 + col], ssq[threadIdx.x] + ssq[threadIdx.x + 128]);
    }
}

// ---------- BN fold into fcW/fcb: one block per output row ----------
__global__ __launch_bounds__(128) void k_bnfold(const float* __restrict__ stats,
                                                const float* __restrict__ gamma, const float* __restrict__ beta,
                                                const float* __restrict__ fcW, const float* __restrict__ fcb,
                                                int M, u16* __restrict__ Wfold, float* __restrict__ bias2) {
    __shared__ float red[128];
    int n = blockIdx.x, t = threadIdx.x;
    float mu = stats[t] / (float)M;
    float var = stats[128 + t] / (float)M - mu * mu;
    float sc = gamma[t] * rsqrtf(var + EPSV);
    float sh = beta[t] - mu * sc;
    float w = fcW[(size_t)n * D + t];
    Wfold[(size_t)n * D + t] = f2bf(w * sc);
    red[t] = sh * w;
    __syncthreads();
    for (int off = 64; off > 0; off >>= 1) {
        if (t < off) red[t] += red[t + off];
        __syncthreads();
    }
    if (t == 0) bias2[n] = fcb[n] + red[0];
}

static inline size_t alup(size_t x) { return (x + 63) & ~(size_t)63; }

extern "C" void kernel_launch(void* const* d_in, const int* in_sizes, int n_in,
                              void* d_out, int out_size, void* d_ws, size_t ws_size,
                              hipStream_t stream) {
    const float* x   = (const float*)d_in[0];
    const int*   ei  = (const int*)d_in[1];
    const float* Wl1 = (const float*)d_in[2];
    const float* bl1 = (const float*)d_in[3];
    const float* Wr1 = (const float*)d_in[4];
    const float* Wl2 = (const float*)d_in[5];
    const float* bl2 = (const float*)d_in[6];
    const float* Wr2 = (const float*)d_in[7];
    const float* gamma = (const float*)d_in[8];
    const float* beta  = (const float*)d_in[9];
    const float* fcW = (const float*)d_in[10];
    const float* fcb = (const float*)d_in[11];
    float* out = (float*)d_out;

    const int M = in_sizes[0] / D;
    const int E = in_sizes[1] / 2;
    const int* srcI = ei;
    const int* dstI = ei + E;
    const int nbuck = (M + BWIDTH - 1) >> BSH;
    const int chunk = (E + NCB - 1) / NCB;

    char* p = (char*)d_ws;
    u16* xb   = (u16*)p;            p += alup((size_t)M * D * 2);
    u16* msgb = (u16*)p;            p += alup((size_t)M * D * 2);
    u16* h1b  = (u16*)p;            p += alup((size_t)M * D * 2);
    u16* h2b  = (u16*)p;            p += alup((size_t)M * D * 2);
    unsigned int* pairs = (unsigned int*)p; p += alup((size_t)E * 4);
    int* csr  = (int*)p;            p += alup((size_t)E * 4);
    int* row_ptr = (int*)p;         p += alup((size_t)(M + 1) * 4);
    int* bh   = (int*)p;            p += alup((size_t)NCB * nbuck * 4);
    int* btot = (int*)p;            p += alup((size_t)nbuck * 4);
    int* bbase= (int*)p;            p += alup((size_t)(nbuck + 1) * 4);
    float* stats = (float*)p;       p += alup(256 * 4);
    u16* Wb   = (u16*)p;            p += alup((size_t)4 * D * D * 2);   // Wl1|Wr1|Wl2|Wr2
    u16* Wfoldb = (u16*)p;          p += alup((size_t)D * D * 2);
    float* bias2 = (float*)p;       p += alup(128 * 4);

    u16* Wl1b = Wb;
    u16* Wr1b = Wb + 16384;
    u16* Wl2b = Wb + 32768;
    u16* Wr2b = Wb + 49152;

    const int nstrips = (M + 127) / 128;
    const int GG = nstrips < 512 ? nstrips : 512;
    const int gather_grid = (M + 15) / 16;

    hipMemsetAsync(stats, 0, 256 * sizeof(float), stream);

    // conversions + CSR build
    k_cvt<<<2048, 256, 0, stream>>>(x, xb, (long long)M * D / 8);
    k_cvt4<<<32, 256, 0, stream>>>(Wl1, Wr1, Wl2, Wr2, Wb);
    k_bhist<<<NCB, 256, 0, stream>>>(dstI, E, chunk, nbuck, bh);
    k_colscan<<<nbuck, NCB, 0, stream>>>(bh, nbuck, btot);
    k_btotscan<<<1, 1024, 0, stream>>>(btot, nbuck, bbase, row_ptr, M, E);
    k_bfill<<<NCB, 256, 0, stream>>>(srcI, dstI, E, chunk, nbuck, bh, bbase, pairs);
    k_b2csr<<<nbuck, 256, 0, stream>>>(pairs, bbase, nbuck, M, row_ptr, csr);

    // layer 1
    k_gather<<<gather_grid, 256, 0, stream>>>(xb, row_ptr, csr, msgb, M);
    k_gemm<1, 1, 1><<<GG, 256, 0, stream>>>(msgb, xb, Wl1b, Wr1b, bl1, h1b, M, nstrips);

    // layer 2
    k_gather<<<gather_grid, 256, 0, stream>>>(h1b, row_ptr, csr, msgb, M);
    k_gemm<1, 1, 1><<<GG, 256, 0, stream>>>(msgb, h1b, Wl2b, Wr2b, bl2, h2b, M, nstrips);

    // batchnorm stats + fold into fc weights
    k_bnstats<<<256, 256, 0, stream>>>(h2b, M, stats);
    k_bnfold<<<128, 128, 0, stream>>>(stats, gamma, beta, fcW, fcb, M, Wfoldb, bias2);

    // final fc (BN folded into Wfold/bias2)
    k_gemm<0, 0, 0><<<GG, 256, 0, stream>>>(h2b, nullptr, Wfoldb, nullptr, bias2, out, M, nstrips);
}

// Round 9
// 436.296 us; speedup vs baseline: 13.4101x; 1.0348x over previous
//
#include <hip/hip_runtime.h>
#include <hip/hip_bf16.h>

#define D 128
#define EPSV 1e-5f
#define BSH 7
#define BWIDTH 128
#define NCB 256          // chunk blocks for bucket hist/fill
#define MAXBUCK 1024

typedef __attribute__((ext_vector_type(8))) short bf16x8;
typedef __attribute__((ext_vector_type(4))) float f32x4;
typedef unsigned short u16;

__device__ inline u16 f2bf(float f) {
    unsigned int u = __builtin_bit_cast(unsigned int, f);
    return (u16)((u + 0x7fffu + ((u >> 16) & 1u)) >> 16);
}
__device__ inline float bf2f(u16 u) {
    unsigned int x = ((unsigned int)u) << 16;
    return __builtin_bit_cast(float, x);
}

__device__ inline void gl_lds16(const void* g, void* l) {
    __builtin_amdgcn_global_load_lds(
        (const __attribute__((address_space(1))) unsigned int*)g,
        (__attribute__((address_space(3))) unsigned int*)l,
        16, 0, 0);
}

// ---------- f32 -> bf16 conversion ----------
__global__ void k_cvt(const float* __restrict__ in, u16* __restrict__ out, long long n8) {
    long long i = (long long)blockIdx.x * blockDim.x + threadIdx.x;
    long long stride = (long long)gridDim.x * blockDim.x;
    for (; i < n8; i += stride) {
        const float4 v0 = *(const float4*)(in + i * 8);
        const float4 v1 = *(const float4*)(in + i * 8 + 4);
        bf16x8 o;
        o[0] = (short)f2bf(v0.x); o[1] = (short)f2bf(v0.y);
        o[2] = (short)f2bf(v0.z); o[3] = (short)f2bf(v0.w);
        o[4] = (short)f2bf(v1.x); o[5] = (short)f2bf(v1.y);
        o[6] = (short)f2bf(v1.z); o[7] = (short)f2bf(v1.w);
        *(bf16x8*)(out + i * 8) = o;
    }
}

// ---------- 4 weight matrices f32->bf16 in one launch (each 128x128) ----------
__global__ __launch_bounds__(256) void k_cvt4(const float* __restrict__ s0, const float* __restrict__ s1,
                                              const float* __restrict__ s2, const float* __restrict__ s3,
                                              u16* __restrict__ out) {
    int i = blockIdx.x * 256 + threadIdx.x;
    int mat = i >> 11;
    int off = (i & 2047) * 8;
    const float* src = (mat == 0) ? s0 : (mat == 1) ? s1 : (mat == 2) ? s2 : s3;
    const float4 v0 = *(const float4*)(src + off);
    const float4 v1 = *(const float4*)(src + off + 4);
    bf16x8 o;
    o[0] = (short)f2bf(v0.x); o[1] = (short)f2bf(v0.y);
    o[2] = (short)f2bf(v0.z); o[3] = (short)f2bf(v0.w);
    o[4] = (short)f2bf(v1.x); o[5] = (short)f2bf(v1.y);
    o[6] = (short)f2bf(v1.z); o[7] = (short)f2bf(v1.w);
    *(bf16x8*)(out + (size_t)i * 8) = o;
}

// ---------- bucket histogram (LDS) ----------
__global__ __launch_bounds__(256) void k_bhist(const int* __restrict__ dst, int E, int chunk,
                                               int nbuck, int* __restrict__ bh) {
    __shared__ int h[MAXBUCK];
    int t = threadIdx.x;
    for (int i = t; i < nbuck; i += 256) h[i] = 0;
    __syncthreads();
    int beg = blockIdx.x * chunk, end = min(E, beg + chunk);
    for (int i = beg + t; i < end; i += 256) atomicAdd(&h[dst[i] >> BSH], 1);
    __syncthreads();
    for (int i = t; i < nbuck; i += 256) bh[(size_t)blockIdx.x * nbuck + i] = h[i];
}

// ---------- column scan ----------
__global__ __launch_bounds__(NCB) void k_colscan(int* __restrict__ bh, int nbuck, int* __restrict__ btot) {
    __shared__ int sm[NCB];
    int b = blockIdx.x;
    int t = threadIdx.x;
    int v = bh[(size_t)t * nbuck + b];
    sm[t] = v;
    __syncthreads();
    for (int off = 1; off < NCB; off <<= 1) {
        int a = (t >= off) ? sm[t - off] : 0;
        __syncthreads();
        sm[t] += a;
        __syncthreads();
    }
    bh[(size_t)t * nbuck + b] = sm[t] - v;
    if (t == NCB - 1) btot[b] = sm[t];
}

// ---------- bucket-total scan -> bbase ----------
__global__ __launch_bounds__(1024) void k_btotscan(const int* __restrict__ btot, int nbuck,
                                                   int* __restrict__ bbase, int* __restrict__ row_ptr,
                                                   int M, int E) {
    __shared__ int sm[1024];
    int t = threadIdx.x;
    int v = (t < nbuck) ? btot[t] : 0;
    sm[t] = v;
    __syncthreads();
    for (int off = 1; off < 1024; off <<= 1) {
        int a = (t >= off) ? sm[t - off] : 0;
        __syncthreads();
        sm[t] += a;
        __syncthreads();
    }
    if (t < nbuck) bbase[t] = sm[t] - v;
    if (t == 0) { bbase[nbuck] = E; row_ptr[M] = E; }
}

// ---------- bucket fill: pairs[pos] = (dstlow<<24) | src ----------
__global__ __launch_bounds__(256) void k_bfill(const int* __restrict__ src, const int* __restrict__ dst,
                                               int E, int chunk, int nbuck, const int* __restrict__ bh,
                                               const int* __restrict__ bbase, unsigned int* __restrict__ pairs) {
    __shared__ int cur[MAXBUCK];
    int t = threadIdx.x;
    for (int i = t; i < nbuck; i += 256)
        cur[i] = bbase[i] + bh[(size_t)blockIdx.x * nbuck + i];
    __syncthreads();
    int beg = blockIdx.x * chunk, end = min(E, beg + chunk);
    for (int i = beg + t; i < end; i += 256) {
        int d = dst[i];
        int bk = d >> BSH;
        int pos = atomicAdd(&cur[bk], 1);
        pairs[pos] = (unsigned int)src[i] | ((unsigned int)(d & (BWIDTH - 1)) << 24);
    }
}

// ---------- per-bucket: node histogram + scan -> row_ptr, csr ----------
__global__ __launch_bounds__(256) void k_b2csr(const unsigned int* __restrict__ pairs,
                                               const int* __restrict__ bbase, int nbuck, int M,
                                               int* __restrict__ row_ptr, int* __restrict__ csr) {
    __shared__ int nh[BWIDTH];
    __shared__ int sc[BWIDTH];
    __shared__ int nc[BWIDTH];
    int b = blockIdx.x;
    int t = threadIdx.x;
    int node0 = b << BSH;
    int beg = bbase[b], end = bbase[b + 1];
    if (t < BWIDTH) nh[t] = 0;
    __syncthreads();
    for (int i = beg + t; i < end; i += 256) atomicAdd(&nh[pairs[i] >> 24], 1);
    __syncthreads();
    if (t < BWIDTH) sc[t] = nh[t];
    __syncthreads();
    for (int off = 1; off < BWIDTH; off <<= 1) {
        int a = 0;
        if (t < BWIDTH && t >= off) a = sc[t - off];
        __syncthreads();
        if (t < BWIDTH) sc[t] += a;
        __syncthreads();
    }
    if (t < BWIDTH) {
        int ex = sc[t] - nh[t];
        nc[t] = ex;
        int node = node0 + t;
        if (node < M) row_ptr[node] = beg + ex;
    }
    __syncthreads();
    for (int i = beg + t; i < end; i += 256) {
        unsigned int p = pairs[i];
        int pos = atomicAdd(&nc[p >> 24], 1);
        csr[beg + pos] = (int)(p & 0xFFFFFFu);
    }
}

// ---------- gather-aggregate (bf16 rows): 16 lanes per node, 8-deep pipeline ----------
__global__ __launch_bounds__(256) void k_gather(const u16* __restrict__ feat, const int* __restrict__ rp,
                                                const int* __restrict__ csr, u16* __restrict__ msg, int M) {
    int sub = threadIdx.x & 15;
    int node = blockIdx.x * 16 + (threadIdx.x >> 4);
    if (node >= M) return;
    int beg = rp[node], end = rp[node + 1];
    float a0[8], a1[8], a2[8], a3[8];
    #pragma unroll
    for (int j = 0; j < 8; j++) { a0[j] = 0.f; a1[j] = 0.f; a2[j] = 0.f; a3[j] = 0.f; }
    int e = beg;
    for (; e + 7 < end; e += 8) {
        int s0 = csr[e], s1 = csr[e + 1], s2 = csr[e + 2], s3 = csr[e + 3];
        int s4 = csr[e + 4], s5 = csr[e + 5], s6 = csr[e + 6], s7 = csr[e + 7];
        bf16x8 v0 = *(const bf16x8*)(feat + (size_t)s0 * D + sub * 8);
        bf16x8 v1 = *(const bf16x8*)(feat + (size_t)s1 * D + sub * 8);
        bf16x8 v2 = *(const bf16x8*)(feat + (size_t)s2 * D + sub * 8);
        bf16x8 v3 = *(const bf16x8*)(feat + (size_t)s3 * D + sub * 8);
        bf16x8 v4 = *(const bf16x8*)(feat + (size_t)s4 * D + sub * 8);
        bf16x8 v5 = *(const bf16x8*)(feat + (size_t)s5 * D + sub * 8);
        bf16x8 v6 = *(const bf16x8*)(feat + (size_t)s6 * D + sub * 8);
        bf16x8 v7 = *(const bf16x8*)(feat + (size_t)s7 * D + sub * 8);
        #pragma unroll
        for (int j = 0; j < 8; j++) {
            a0[j] += bf2f((u16)v0[j]); a1[j] += bf2f((u16)v1[j]);
            a2[j] += bf2f((u16)v2[j]); a3[j] += bf2f((u16)v3[j]);
            a0[j] += bf2f((u16)v4[j]); a1[j] += bf2f((u16)v5[j]);
            a2[j] += bf2f((u16)v6[j]); a3[j] += bf2f((u16)v7[j]);
        }
    }
    for (; e + 3 < end; e += 4) {
        int s0 = csr[e], s1 = csr[e + 1], s2 = csr[e + 2], s3 = csr[e + 3];
        bf16x8 v0 = *(const bf16x8*)(feat + (size_t)s0 * D + sub * 8);
        bf16x8 v1 = *(const bf16x8*)(feat + (size_t)s1 * D + sub * 8);
        bf16x8 v2 = *(const bf16x8*)(feat + (size_t)s2 * D + sub * 8);
        bf16x8 v3 = *(const bf16x8*)(feat + (size_t)s3 * D + sub * 8);
        #pragma unroll
        for (int j = 0; j < 8; j++) {
            a0[j] += bf2f((u16)v0[j]); a1[j] += bf2f((u16)v1[j]);
            a2[j] += bf2f((u16)v2[j]); a3[j] += bf2f((u16)v3[j]);
        }
    }
    for (; e < end; e++) {
        bf16x8 v0 = *(const bf16x8*)(feat + (size_t)csr[e] * D + sub * 8);
        #pragma unroll
        for (int j = 0; j < 8; j++) a0[j] += bf2f((u16)v0[j]);
    }
    float inv = 1.0f / fmaxf((float)(end - beg), 1.0f);
    bf16x8 o;
    #pragma unroll
    for (int j = 0; j < 8; j++) o[j] = (short)f2bf((a0[j] + a1[j] + a2[j] + a3[j]) * inv);
    *(bf16x8*)(msg + (size_t)node * D + sub * 8) = o;
}

// ---- fused GEMM v4: persistent 64-row strips, W LDS-resident (XOR-swizzled),
// A double-buffered into LDS via async global_load_lds with inverse-swizzled source.
// C = act( A1 @ W1^T [+ A2 @ W2^T] + bias ); A,W bf16
template <int TWO, int RELU, int OUTBF>
__global__ __launch_bounds__(256) void k_gemm(
    const u16* __restrict__ A1, const u16* __restrict__ A2,
    const u16* __restrict__ W1b, const u16* __restrict__ W2b,
    const float* __restrict__ bias, void* __restrict__ Cout,
    int M, int nstrips) {
    constexpr int NOPS = TWO ? 2 : 1;
    // layout (u16): W [NOPS][128][128], then A [2 buf][NOPS][64][128]
    __shared__ __align__(16) u16 lds[NOPS * 16384 + 2 * NOPS * 8192];
    u16* wlds = lds;
    u16* alds = lds + NOPS * 16384;

    int t = threadIdx.x;
    int lane = t & 63, wave = t >> 6;
    int rlo = lane & 15, khi = lane >> 4;

    // --- async stage of one 64-row strip into buffer buf ---
    auto stage = [&](int buf, int sidx) {
        int rsub = khi;             // row within 4-row chunk
        #pragma unroll
        for (int c = 0; c < 4; c++) {
            int chunk = wave * 4 + c;
            int lrow = chunk * 4 + rsub;
            int ra = sidx * 64 + lrow;
            if (ra > M - 1) ra = M - 1;
            int src16 = rlo ^ (lrow & 7);
            gl_lds16(A1 + (size_t)ra * D + src16 * 8,
                     alds + ((size_t)buf * NOPS + 0) * 8192 + chunk * 512);
            if (TWO)
                gl_lds16(A2 + (size_t)ra * D + src16 * 8,
                         alds + ((size_t)buf * NOPS + 1) * 8192 + chunk * 512);
        }
    };

    int s0 = blockIdx.x;
    if (s0 < nstrips) stage(0, s0);

    // stage W (row-major 128x128 bf16 per op) with c16 ^= row&7 swizzle
    {
        const int nrows = NOPS * 128;
        for (int idx = t; idx < nrows; idx += 256) {
            int mat = idx >> 7, row = idx & 127;
            const u16* g = (mat ? W2b : W1b) + (size_t)row * D;
            u16* base = wlds + mat * 16384 + row * D;
            #pragma unroll
            for (int c16 = 0; c16 < 16; c16++) {
                bf16x8 v = *(const bf16x8*)(g + c16 * 8);
                *(bf16x8*)(base + ((c16 ^ (row & 7)) * 8)) = v;
            }
        }
    }
    __syncthreads();

    int cur = 0;
    for (int s = s0; s < nstrips; s += gridDim.x) {
        int nxt = s + gridDim.x;
        if (nxt < nstrips) stage(cur ^ 1, nxt);

        // A fragments from LDS: local row = wave*16 + rlo, k = kk*32 + khi*8
        int r_local = wave * 16 + rlo;
        bf16x8 af[NOPS][4];
        #pragma unroll
        for (int o = 0; o < NOPS; o++) {
            const u16* ab = alds + ((size_t)cur * NOPS + o) * 8192 + r_local * D;
            #pragma unroll
            for (int kk = 0; kk < 4; kk++)
                af[o][kk] = *(const bf16x8*)(ab + (((kk * 4 + khi) ^ (r_local & 7)) * 8));
        }

        f32x4 acc[8];
        #pragma unroll
        for (int nt = 0; nt < 8; nt++) acc[nt] = (f32x4){0.f, 0.f, 0.f, 0.f};

        #pragma unroll
        for (int nt = 0; nt < 8; nt++) {
            int row = nt * 16 + rlo;
            #pragma unroll
            for (int o = 0; o < NOPS; o++) {
                const u16* wb = wlds + o * 16384 + (size_t)row * D;
                bf16x8 wf[4];
                #pragma unroll
                for (int kk = 0; kk < 4; kk++)
                    wf[kk] = *(const bf16x8*)(wb + (((kk * 4 + khi) ^ (row & 7)) * 8));
                #pragma unroll
                for (int kk = 0; kk < 4; kk++)
                    acc[nt] = __builtin_amdgcn_mfma_f32_16x16x32_bf16(af[o][kk], wf[kk], acc[nt], 0, 0, 0);
            }
        }

        // C/D: col = lane&15, row = khi*4 + r
        int mrow0 = s * 64 + wave * 16 + khi * 4;
        #pragma unroll
        for (int nt = 0; nt < 8; nt++) {
            int col = nt * 16 + rlo;
            float bn = bias[col];
            #pragma unroll
            for (int r = 0; r < 4; r++) {
                int row = mrow0 + r;
                if (row < M) {
                    float v = acc[nt][r] + bn;
                    if (RELU) v = fmaxf(v, 0.0f);
                    if (OUTBF) ((u16*)Cout)[(size_t)row * D + col] = f2bf(v);
                    else       ((float*)Cout)[(size_t)row * D + col] = v;
                }
            }
        }

        // wait for stage loads (issued before the C-stores; in-order retirement)
        asm volatile("s_waitcnt vmcnt(32)" ::: "memory");
        __syncthreads();
        cur ^= 1;
    }
}

// ---------- batchnorm stats (bf16 input, LDS pre-reduce, few atomics) ----------
__global__ __launch_bounds__(256) void k_bnstats(const u16* __restrict__ h, int M, float* __restrict__ stats) {
    __shared__ float ssum[256];
    __shared__ float ssq[256];
    int col = threadIdx.x & 127;
    int half = threadIdx.x >> 7;
    float s = 0.f, s2 = 0.f;
    for (int r = blockIdx.x * 2 + half; r < M; r += 512) {
        float v = bf2f(h[(size_t)r * D + col]);
        s += v;
        s2 += v * v;
    }
    ssum[threadIdx.x] = s;
    ssq[threadIdx.x] = s2;
    __syncthreads();
    if (threadIdx.x < 128) {
        unsafeAtomicAdd(&stats[col], ssum[threadIdx.x] + ssum[threadIdx.x + 128]);
        unsafeAtomicAdd(&stats[128 + col], ssq[threadIdx.x] + ssq[threadIdx.x + 128]);
    }
}

// ---------- BN fold into fcW/fcb: one block per output row ----------
__global__ __launch_bounds__(128) void k_bnfold(const float* __restrict__ stats,
                                                const float* __restrict__ gamma, const float* __restrict__ beta,
                                                const float* __restrict__ fcW, const float* __restrict__ fcb,
                                                int M, u16* __restrict__ Wfold, float* __restrict__ bias2) {
    __shared__ float red[128];
    int n = blockIdx.x, t = threadIdx.x;
    float mu = stats[t] / (float)M;
    float var = stats[128 + t] / (float)M - mu * mu;
    float sc = gamma[t] * rsqrtf(var + EPSV);
    float sh = beta[t] - mu * sc;
    float w = fcW[(size_t)n * D + t];
    Wfold[(size_t)n * D + t] = f2bf(w * sc);
    red[t] = sh * w;
    __syncthreads();
    for (int off = 64; off > 0; off >>= 1) {
        if (t < off) red[t] += red[t + off];
        __syncthreads();
    }
    if (t == 0) bias2[n] = fcb[n] + red[0];
}

static inline size_t alup(size_t x) { return (x + 63) & ~(size_t)63; }

extern "C" void kernel_launch(void* const* d_in, const int* in_sizes, int n_in,
                              void* d_out, int out_size, void* d_ws, size_t ws_size,
                              hipStream_t stream) {
    const float* x   = (const float*)d_in[0];
    const int*   ei  = (const int*)d_in[1];
    const float* Wl1 = (const float*)d_in[2];
    const float* bl1 = (const float*)d_in[3];
    const float* Wr1 = (const float*)d_in[4];
    const float* Wl2 = (const float*)d_in[5];
    const float* bl2 = (const float*)d_in[6];
    const float* Wr2 = (const float*)d_in[7];
    const float* gamma = (const float*)d_in[8];
    const float* beta  = (const float*)d_in[9];
    const float* fcW = (const float*)d_in[10];
    const float* fcb = (const float*)d_in[11];
    float* out = (float*)d_out;

    const int M = in_sizes[0] / D;
    const int E = in_sizes[1] / 2;
    const int* srcI = ei;
    const int* dstI = ei + E;
    const int nbuck = (M + BWIDTH - 1) >> BSH;
    const int chunk = (E + NCB - 1) / NCB;

    char* p = (char*)d_ws;
    u16* xb   = (u16*)p;            p += alup((size_t)M * D * 2);
    u16* msgb = (u16*)p;            p += alup((size_t)M * D * 2);
    u16* h1b  = (u16*)p;            p += alup((size_t)M * D * 2);
    u16* h2b  = (u16*)p;            p += alup((size_t)M * D * 2);
    unsigned int* pairs = (unsigned int*)p; p += alup((size_t)E * 4);
    int* csr  = (int*)p;            p += alup((size_t)E * 4);
    int* row_ptr = (int*)p;         p += alup((size_t)(M + 1) * 4);
    int* bh   = (int*)p;            p += alup((size_t)NCB * nbuck * 4);
    int* btot = (int*)p;            p += alup((size_t)nbuck * 4);
    int* bbase= (int*)p;            p += alup((size_t)(nbuck + 1) * 4);
    float* stats = (float*)p;       p += alup(256 * 4);
    u16* Wb   = (u16*)p;            p += alup((size_t)4 * D * D * 2);   // Wl1|Wr1|Wl2|Wr2
    u16* Wfoldb = (u16*)p;          p += alup((size_t)D * D * 2);
    float* bias2 = (float*)p;       p += alup(128 * 4);

    u16* Wl1b = Wb;
    u16* Wr1b = Wb + 16384;
    u16* Wl2b = Wb + 32768;
    u16* Wr2b = Wb + 49152;

    const int nstrips = (M + 63) / 64;
    const int GG2 = 256;                 // TWO kernels: 128KB LDS -> 1 block/CU
    const int GG1 = 512;                 // fc: 64KB LDS -> 2 blocks/CU
    const int gather_grid = (M + 15) / 16;

    hipMemsetAsync(stats, 0, 256 * sizeof(float), stream);

    // conversions + CSR build
    k_cvt<<<2048, 256, 0, stream>>>(x, xb, (long long)M * D / 8);
    k_cvt4<<<32, 256, 0, stream>>>(Wl1, Wr1, Wl2, Wr2, Wb);
    k_bhist<<<NCB, 256, 0, stream>>>(dstI, E, chunk, nbuck, bh);
    k_colscan<<<nbuck, NCB, 0, stream>>>(bh, nbuck, btot);
    k_btotscan<<<1, 1024, 0, stream>>>(btot, nbuck, bbase, row_ptr, M, E);
    k_bfill<<<NCB, 256, 0, stream>>>(srcI, dstI, E, chunk, nbuck, bh, bbase, pairs);
    k_b2csr<<<nbuck, 256, 0, stream>>>(pairs, bbase, nbuck, M, row_ptr, csr);

    // layer 1
    k_gather<<<gather_grid, 256, 0, stream>>>(xb, row_ptr, csr, msgb, M);
    k_gemm<1, 1, 1><<<GG2, 256, 0, stream>>>(msgb, xb, Wl1b, Wr1b, bl1, h1b, M, nstrips);

    // layer 2
    k_gather<<<gather_grid, 256, 0, stream>>>(h1b, row_ptr, csr, msgb, M);
    k_gemm<1, 1, 1><<<GG2, 256, 0, stream>>>(msgb, h1b, Wl2b, Wr2b, bl2, h2b, M, nstrips);

    // batchnorm stats + fold into fc weights
    k_bnstats<<<256, 256, 0, stream>>>(h2b, M, stats);
    k_bnfold<<<128, 128, 0, stream>>>(stats, gamma, beta, fcW, fcb, M, Wfoldb, bias2);

    // final fc (BN folded into Wfold/bias2)
    k_gemm<0, 0, 0><<<GG1, 256, 0, stream>>>(h2b, nullptr, Wfoldb, nullptr, bias2, out, M, nstrips);
}